// Round 7
// baseline (4485.016 us; speedup 1.0000x reference)
//
#include <hip/hip_runtime.h>
#include <cstdint>

// ============================================================================
// ViT forward, MI355X round 6.
//   R6 change vs R5: ALL GEMMs on gemmP (128x128, BK=64, dbuf 64 KiB LDS ->
//   2 blocks/CU). In-run A/B (R5/R6 profiles) showed gemmP ~700 TF vs
//   gemm8 442 TF at identical FLOPs on this workload's K=768/3072 shapes:
//   the 256^2 8-phase needs NT>=64 steady state + 1 block/CU has no
//   co-resident overlap partner. gemm8 deleted.
// ============================================================================

typedef __attribute__((ext_vector_type(8))) short bf16x8;
typedef __attribute__((ext_vector_type(4))) float f32x4;

#define NTOK 577

__device__ __forceinline__ ushort f2bf(float f) {
  union { float f; unsigned int u; } x; x.f = f;
  unsigned int r = x.u + 0x7fffu + ((x.u >> 16) & 1u);  // RNE
  return (ushort)(r >> 16);
}

__device__ __forceinline__ void gload_lds16(const ushort* g, ushort* l) {
  __builtin_amdgcn_global_load_lds(
      (const __attribute__((address_space(1))) unsigned int*)g,
      (__attribute__((address_space(3))) unsigned int*)l, 16, 0, 0);
}

#define VMCNT0 asm volatile("s_waitcnt vmcnt(0)" ::: "memory")
#define LGKM0  asm volatile("s_waitcnt lgkmcnt(0)" ::: "memory")
#define SCHED0 __builtin_amdgcn_sched_barrier(0)
#define BARRIER __builtin_amdgcn_s_barrier()

// rotation swizzle: logical 16B-granule at row -> physical granule rotation
__device__ __forceinline__ int gsw(int row) {
  return (row & 7) + 2 * ((row >> 4) & 3);
}

// ---------------------------------------------------------------------------
// f32 W[K][N]  ->  bf16 Wt[N][K]   (tiled transpose, coalesced both sides)
// ---------------------------------------------------------------------------
__global__ __launch_bounds__(256) void convt_kernel(const float* __restrict__ W,
                                                    ushort* __restrict__ Wt,
                                                    int K, int N) {
  __shared__ float t[32][33];
  const int kb = blockIdx.x * 32, nb = blockIdx.y * 32;
  const int tx = threadIdx.x & 31, ty = threadIdx.x >> 5;
#pragma unroll
  for (int i = 0; i < 32; i += 8)
    t[ty + i][tx] = W[(size_t)(kb + ty + i) * N + (nb + tx)];
  __syncthreads();
#pragma unroll
  for (int i = 0; i < 32; i += 8)
    Wt[(size_t)(nb + ty + i) * K + (kb + tx)] = f2bf(t[tx][ty + i]);
}

// ---------------------------------------------------------------------------
// im2col: img (B,3,384,384) f32 -> Apatch (9216 x 768) bf16
// ---------------------------------------------------------------------------
__global__ __launch_bounds__(256) void im2col_kernel(const float* __restrict__ img,
                                                     ushort* __restrict__ Ap) {
  const int idx = blockIdx.x * 256 + threadIdx.x;  // 9216*768 exactly
  const int j = idx % 768;
  const int m = idx / 768;
  const int c = j % 3;
  const int q = j / 3;
  const int px = q & 15, py = q >> 4;
  const int b = m / 576, p = m % 576;
  const int gy = p / 24, gx = p % 24;
  const float v = img[((size_t)(b * 3 + c) * 384 + (gy * 16 + py)) * 384 + (gx * 16 + px)];
  Ap[idx] = f2bf(v);
}

__global__ void clspos_kernel(const float* __restrict__ cls_tok,
                              const float* __restrict__ pos,
                              float* __restrict__ x) {
  const int i = blockIdx.x * 256 + threadIdx.x;  // 16*768
  const int b = i / 768, d = i % 768;
  x[(size_t)b * NTOK * 768 + d] = cls_tok[d] + pos[d];
}

// ---------------------------------------------------------------------------
// LayerNorm row kernel: x f32 row (768) -> bf16 out row. 1 wave per row.
// ---------------------------------------------------------------------------
__global__ __launch_bounds__(64) void ln_kernel(const float* __restrict__ x,
                                                const float* __restrict__ w,
                                                const float* __restrict__ bb,
                                                ushort* __restrict__ out) {
  const int row = blockIdx.x, lane = threadIdx.x;
  const float4* xr = reinterpret_cast<const float4*>(x + (size_t)row * 768);
  const float4 v0 = xr[lane], v1 = xr[lane + 64], v2 = xr[lane + 128];
  float vals[12] = {v0.x, v0.y, v0.z, v0.w, v1.x, v1.y, v1.z, v1.w,
                    v2.x, v2.y, v2.z, v2.w};
  float s = 0.f;
#pragma unroll
  for (int i = 0; i < 12; ++i) s += vals[i];
#pragma unroll
  for (int o = 32; o; o >>= 1) s += __shfl_xor(s, o);
  const float mu = s * (1.0f / 768.0f);
  float q = 0.f;
#pragma unroll
  for (int i = 0; i < 12; ++i) { const float d = vals[i] - mu; q += d * d; }
#pragma unroll
  for (int o = 32; o; o >>= 1) q += __shfl_xor(q, o);
  const float rstd = rsqrtf(q * (1.0f / 768.0f) + 1e-5f);
  const float4* w4 = reinterpret_cast<const float4*>(w);
  const float4* b4 = reinterpret_cast<const float4*>(bb);
  ushort* orow = out + (size_t)row * 768;
#pragma unroll
  for (int ch = 0; ch < 3; ++ch) {
    const float4 wv = w4[lane + ch * 64];
    const float4 bv = b4[lane + ch * 64];
    ushort4 u;
    u.x = f2bf((vals[ch * 4 + 0] - mu) * rstd * wv.x + bv.x);
    u.y = f2bf((vals[ch * 4 + 1] - mu) * rstd * wv.y + bv.y);
    u.z = f2bf((vals[ch * 4 + 2] - mu) * rstd * wv.z + bv.z);
    u.w = f2bf((vals[ch * 4 + 3] - mu) * rstd * wv.w + bv.w);
    *reinterpret_cast<ushort4*>(orow + ch * 256 + lane * 4) = u;
  }
}

// ---------------------------------------------------------------------------
// Epilogue IDs
// ---------------------------------------------------------------------------
constexpr int EPI_BF16 = 0;       // C = acc                     -> bf16
constexpr int EPI_GELU_BF16 = 1;  // C = gelu(acc + bias)        -> bf16
constexpr int EPI_RES_F32 = 2;    // C = acc + bias + extra[r,c] -> f32
constexpr int EPI_PATCH = 3;      // x[row+b+1] = acc + patch_b + pos[p+1]

// ---------------------------------------------------------------------------
// gemmP: 128x128 tile, BK=64, dbuf LDS 64 KiB (2 blocks/CU), 256 thr =
// 4 waves (2M x 2N, per-wave 64x64). Per K-tile: one vmcnt(0)+barrier,
// stage-all of tile t+1 issued right after the barrier, 16 ds_read_b128,
// 32 MFMA under setprio. Rotation swizzle (pre-swizzled global source +
// swizzled ds_read). Cross-block overlap (2/CU) hides the stage drain.
// ---------------------------------------------------------------------------
template <int EPI>
__global__ __launch_bounds__(256) void gemmP_kernel(
    const ushort* __restrict__ A, const ushort* __restrict__ Bt,
    const float* __restrict__ bias, const float* __restrict__ extra,
    void* __restrict__ Cptr, int M, int N, int K, int mt) {
  __shared__ ushort ldsA[2][128 * 64];
  __shared__ ushort ldsB[2][128 * 64];

  // bijective XCD swizzle (m204)
  const int nwg = gridDim.x;
  const int orig = blockIdx.x;
  const int q8 = nwg >> 3, r8 = nwg & 7, xcd = orig & 7, sidx = orig >> 3;
  const int wg = (xcd < r8 ? xcd * (q8 + 1) : r8 * (q8 + 1) + (xcd - r8) * q8) + sidx;
  const int tileM = (wg % mt) * 128;
  const int tileN = (wg / mt) * 128;

  const int tid = threadIdx.x;
  const int wave = tid >> 6, lane = tid & 63;
  const int wm = wave >> 1, wn = wave & 1;
  const int lr = lane & 15, lg = lane >> 4;

  f32x4 acc[4][4];
#pragma unroll
  for (int m = 0; m < 4; ++m)
#pragma unroll
    for (int n = 0; n < 4; ++n) acc[m][n] = (f32x4){0.f, 0.f, 0.f, 0.f};

  // staging: 16 A-chunks + 16 B-chunks of 8 rows (1 KiB each); wave w owns
  // chunks 4w..4w+3 of each. Per-lane source pre-swizzled by gsw(row).
  const ushort* pA[4];
  const ushort* pB[4];
  int dst[4];
#pragma unroll
  for (int i = 0; i < 4; ++i) {
    const int c = wave * 4 + i;
    const int rowst = c * 8;
    dst[i] = rowst * 64;
    const int row = rowst + (lane >> 3);
    const int lgr = ((lane & 7) - gsw(row)) & 7;
    pA[i] = A + (size_t)(tileM + row) * K + lgr * 8;
    pB[i] = Bt + (size_t)(tileN + row) * K + lgr * 8;
  }

#define PSTAGE(buf, kk)                              \
  _Pragma("unroll") for (int i = 0; i < 4; ++i)      \
      gload_lds16(pA[i] + (kk), &ldsA[buf][dst[i]]); \
  _Pragma("unroll") for (int i = 0; i < 4; ++i)      \
      gload_lds16(pB[i] + (kk), &ldsB[buf][dst[i]]);

  PSTAGE(0, 0);

  const int NT = K >> 6;
  int cb = 0;
  for (int t = 0; t < NT; ++t) {
    VMCNT0; SCHED0;   // own loads of tile t landed
    BARRIER;          // all waves' loads landed
    if (t + 1 < NT) { PSTAGE(cb ^ 1, (t + 1) * 64); }
    bf16x8 a[8], b[8];
#pragma unroll
    for (int mf = 0; mf < 4; ++mf) {
      const int row = wm * 64 + mf * 16 + lr;
#pragma unroll
      for (int ks = 0; ks < 2; ++ks) {
        const int pg = (ks * 4 + lg + (lr & 7) + 2 * mf) & 7;
        a[mf * 2 + ks] = *reinterpret_cast<const bf16x8*>(&ldsA[cb][row * 64 + pg * 8]);
      }
    }
#pragma unroll
    for (int nf = 0; nf < 4; ++nf) {
      const int row = wn * 64 + nf * 16 + lr;
#pragma unroll
      for (int ks = 0; ks < 2; ++ks) {
        const int pg = (ks * 4 + lg + (lr & 7) + 2 * nf) & 7;
        b[nf * 2 + ks] = *reinterpret_cast<const bf16x8*>(&ldsB[cb][row * 64 + pg * 8]);
      }
    }
    LGKM0; SCHED0;
    __builtin_amdgcn_s_setprio(1);
#pragma unroll
    for (int mf = 0; mf < 4; ++mf)
#pragma unroll
      for (int nf = 0; nf < 4; ++nf)
#pragma unroll
        for (int ks = 0; ks < 2; ++ks)
          acc[mf][nf] = __builtin_amdgcn_mfma_f32_16x16x32_bf16(
              a[mf * 2 + ks], b[nf * 2 + ks], acc[mf][nf], 0, 0, 0);
    __builtin_amdgcn_s_setprio(0);
    cb ^= 1;
  }

  // epilogue: row = tileM + wm*64 + mf*16 + lg*4 + r ; col = tileN + wn*64 + nf*16 + lr
#pragma unroll
  for (int mf = 0; mf < 4; ++mf) {
#pragma unroll
    for (int r = 0; r < 4; ++r) {
      const int row = tileM + wm * 64 + mf * 16 + lg * 4 + r;
      if (row >= M) continue;
#pragma unroll
      for (int nf = 0; nf < 4; ++nf) {
        const int col = tileN + wn * 64 + nf * 16 + lr;
        float v = acc[mf][nf][r];
        if constexpr (EPI == EPI_BF16) {
          reinterpret_cast<ushort*>(Cptr)[(size_t)row * N + col] = f2bf(v);
        } else if constexpr (EPI == EPI_GELU_BF16) {
          v += bias[col];
          v = 0.5f * v * (1.0f + erff(v * 0.70710678118654752440f));
          reinterpret_cast<ushort*>(Cptr)[(size_t)row * N + col] = f2bf(v);
        } else if constexpr (EPI == EPI_RES_F32) {
          v += bias[col] + extra[(size_t)row * N + col];
          reinterpret_cast<float*>(Cptr)[(size_t)row * N + col] = v;
        } else {  // EPI_PATCH: row = b*576+p -> x row b*577+1+p
          const int bb = row / 576;
          const int p = row - bb * 576;
          v += bias[col] + extra[(size_t)(p + 1) * 768 + col];
          reinterpret_cast<float*>(Cptr)[(size_t)(row + bb + 1) * 768 + col] = v;
        }
      }
    }
  }
#undef PSTAGE
}

// ---------------------------------------------------------------------------
// MFMA flash attention with rotation-swizzled LDS. Unchanged.
// ---------------------------------------------------------------------------
__global__ __launch_bounds__(256) void attn_kernel(const ushort* __restrict__ qkv,
                                                   ushort* __restrict__ o) {
  __shared__ ushort sK[64 * 64];
  __shared__ ushort sVt[64 * 64];
  __shared__ ushort sP[4][16 * 72];
  const int bh = blockIdx.x;
  const int b = bh / 12, hh = bh % 12;
  const int q0 = blockIdx.y * 64;
  const int tid = threadIdx.x;
  const int wave = tid >> 6, lane = tid & 63;
  const int lr = lane & 15;
  const int lg = lane >> 4;
  const ushort* base = qkv + (size_t)b * NTOK * 2304 + hh * 64;
  const float SC = 0.03608439182435161f;  // 768^-0.5

  bf16x8 qf[2];
  {
    const int qrow = q0 + wave * 16 + lr;
    if (qrow < NTOK) {
      const ushort* qp = base + (size_t)qrow * 2304 + lg * 8;
      qf[0] = *reinterpret_cast<const bf16x8*>(qp);
      qf[1] = *reinterpret_cast<const bf16x8*>(qp + 32);
    } else {
      qf[0] = (bf16x8){0, 0, 0, 0, 0, 0, 0, 0};
      qf[1] = qf[0];
    }
  }

  float mst[4], lst[4];
  f32x4 oacc[4];
#pragma unroll
  for (int i = 0; i < 4; ++i) {
    mst[i] = -1e30f; lst[i] = 0.f;
    oacc[i] = (f32x4){0.f, 0.f, 0.f, 0.f};
  }

  const int skey = tid >> 2;
  const int sc4 = tid & 3;
  const int gswk = gsw(skey);

  for (int t0 = 0; t0 < NTOK; t0 += 64) {
    __syncthreads();
    {
      const int gk = t0 + skey;
      int4 k0v, k1v, v0v, v1v;
      if (gk < NTOK) {
        const int4* kp = reinterpret_cast<const int4*>(base + (size_t)gk * 2304 + 768 + sc4 * 16);
        k0v = kp[0]; k1v = kp[1];
        const int4* vp = reinterpret_cast<const int4*>(base + (size_t)gk * 2304 + 1536 + sc4 * 16);
        v0v = vp[0]; v1v = vp[1];
      } else {
        int4 z; z.x = z.y = z.z = z.w = 0;
        k0v = k1v = v0v = v1v = z;
      }
      *reinterpret_cast<int4*>(&sK[skey * 64 + (((2 * sc4 + 0) + gswk) & 7) * 8]) = k0v;
      *reinterpret_cast<int4*>(&sK[skey * 64 + (((2 * sc4 + 1) + gswk) & 7) * 8]) = k1v;
      const ushort* vs = reinterpret_cast<const ushort*>(&v0v);
      const ushort* vs2 = reinterpret_cast<const ushort*>(&v1v);
#pragma unroll
      for (int i = 0; i < 8; ++i) {
        const int d0 = sc4 * 16 + i;
        const int pg0 = ((skey >> 3) + gsw(d0)) & 7;
        sVt[d0 * 64 + pg0 * 8 + (skey & 7)] = vs[i];
        const int d1 = sc4 * 16 + 8 + i;
        const int pg1 = ((skey >> 3) + gsw(d1)) & 7;
        sVt[d1 * 64 + pg1 * 8 + (skey & 7)] = vs2[i];
      }
    }
    __syncthreads();

    f32x4 sacc[4];
#pragma unroll
    for (int n = 0; n < 4; ++n) sacc[n] = (f32x4){0.f, 0.f, 0.f, 0.f};
#pragma unroll
    for (int n = 0; n < 4; ++n) {
      const int row = n * 16 + lr;
      const int rot = (lr & 7) + 2 * n;
      const bf16x8 kf0 = *reinterpret_cast<const bf16x8*>(&sK[row * 64 + ((lg + rot) & 7) * 8]);
      const bf16x8 kf1 = *reinterpret_cast<const bf16x8*>(&sK[row * 64 + ((4 + lg + rot) & 7) * 8]);
      sacc[n] = __builtin_amdgcn_mfma_f32_16x16x32_bf16(qf[0], kf0, sacc[n], 0, 0, 0);
      sacc[n] = __builtin_amdgcn_mfma_f32_16x16x32_bf16(qf[1], kf1, sacc[n], 0, 0, 0);
    }

    float s[4][4], pm[4];
#pragma unroll
    for (int reg = 0; reg < 4; ++reg) pm[reg] = -1e30f;
#pragma unroll
    for (int n = 0; n < 4; ++n)
#pragma unroll
      for (int reg = 0; reg < 4; ++reg) {
        float v = sacc[n][reg] * SC;
        if (t0 + n * 16 + lr >= NTOK) v = -1e30f;
        s[n][reg] = v;
        pm[reg] = fmaxf(pm[reg], v);
      }
#pragma unroll
    for (int off = 1; off < 16; off <<= 1)
#pragma unroll
      for (int reg = 0; reg < 4; ++reg) pm[reg] = fmaxf(pm[reg], __shfl_xor(pm[reg], off));

    float al[4], rs[4];
#pragma unroll
    for (int reg = 0; reg < 4; ++reg) {
      const float mn = fmaxf(mst[reg], pm[reg]);
      al[reg] = __expf(mst[reg] - mn);
      mst[reg] = mn;
      rs[reg] = 0.f;
    }
#pragma unroll
    for (int n = 0; n < 4; ++n)
#pragma unroll
      for (int reg = 0; reg < 4; ++reg) {
        s[n][reg] = __expf(s[n][reg] - mst[reg]);
        rs[reg] += s[n][reg];
      }
#pragma unroll
    for (int off = 1; off < 16; off <<= 1)
#pragma unroll
      for (int reg = 0; reg < 4; ++reg) rs[reg] += __shfl_xor(rs[reg], off);
#pragma unroll
    for (int reg = 0; reg < 4; ++reg) {
      lst[reg] = lst[reg] * al[reg] + rs[reg];
#pragma unroll
      for (int n = 0; n < 4; ++n) oacc[n][reg] *= al[reg];
    }

#pragma unroll
    for (int n = 0; n < 4; ++n)
#pragma unroll
      for (int reg = 0; reg < 4; ++reg)
        sP[wave][(lg * 4 + reg) * 72 + n * 16 + lr] = f2bf(s[n][reg]);

    const bf16x8 pf0 = *reinterpret_cast<const bf16x8*>(&sP[wave][lr * 72 + lg * 8]);
    const bf16x8 pf1 = *reinterpret_cast<const bf16x8*>(&sP[wave][lr * 72 + 32 + lg * 8]);
#pragma unroll
    for (int n = 0; n < 4; ++n) {
      const int row = n * 16 + lr;
      const int rot = (lr & 7) + 2 * n;
      const bf16x8 vf0 = *reinterpret_cast<const bf16x8*>(&sVt[row * 64 + ((lg + rot) & 7) * 8]);
      const bf16x8 vf1 = *reinterpret_cast<const bf16x8*>(&sVt[row * 64 + ((4 + lg + rot) & 7) * 8]);
      oacc[n] = __builtin_amdgcn_mfma_f32_16x16x32_bf16(pf0, vf0, oacc[n], 0, 0, 0);
      oacc[n] = __builtin_amdgcn_mfma_f32_16x16x32_bf16(pf1, vf1, oacc[n], 0, 0, 0);
    }
  }

#pragma unroll
  for (int reg = 0; reg < 4; ++reg) {
    const int q = q0 + wave * 16 + lg * 4 + reg;
    if (q >= NTOK) continue;
    const float inv = 1.0f / lst[reg];
    ushort* op = o + (size_t)(b * NTOK + q) * 768 + hh * 64;
#pragma unroll
    for (int n = 0; n < 4; ++n) op[n * 16 + lr] = f2bf(oacc[n][reg] * inv);
  }
}

// ---------------------------------------------------------------------------
// Head: LN(cls rows) @ head_w (768x1000) + head_b -> out (16x1000) f32
// ---------------------------------------------------------------------------
__global__ __launch_bounds__(256) void head_kernel(const float* __restrict__ x,
                                                   const float* __restrict__ lw,
                                                   const float* __restrict__ lb,
                                                   const float* __restrict__ hw,
                                                   const float* __restrict__ hb,
                                                   float* __restrict__ out) {
  __shared__ float srow[768];
  __shared__ float sred[8];
  const int b = blockIdx.x, tid = threadIdx.x;
  const float* xr = x + (size_t)b * NTOK * 768;
  for (int i = tid; i < 768; i += 256) srow[i] = xr[i];
  __syncthreads();
  float part = srow[tid] + srow[tid + 256] + srow[tid + 512];
#pragma unroll
  for (int off = 32; off; off >>= 1) part += __shfl_xor(part, off);
  if ((tid & 63) == 0) sred[tid >> 6] = part;
  __syncthreads();
  const float mu = (sred[0] + sred[1] + sred[2] + sred[3]) * (1.0f / 768.0f);
  const float d0 = srow[tid] - mu, d1 = srow[tid + 256] - mu, d2 = srow[tid + 512] - mu;
  float vp = d0 * d0 + d1 * d1 + d2 * d2;
#pragma unroll
  for (int off = 32; off; off >>= 1) vp += __shfl_xor(vp, off);
  if ((tid & 63) == 0) sred[4 + (tid >> 6)] = vp;
  __syncthreads();
  const float rstd = rsqrtf((sred[4] + sred[5] + sred[6] + sred[7]) * (1.0f / 768.0f) + 1e-5f);
  for (int i = tid; i < 768; i += 256) srow[i] = (srow[i] - mu) * rstd * lw[i] + lb[i];
  __syncthreads();
  const int c = blockIdx.y * 250 + tid;
  if (tid < 250 && c < 1000) {
    float a = 0.f;
#pragma unroll 4
    for (int k = 0; k < 768; ++k) a += srow[k] * hw[(size_t)k * 1000 + c];
    out[b * 1000 + c] = a + hb[c];
  }
}

// ---------------------------------------------------------------------------
extern "C" void kernel_launch(void* const* d_in, const int* in_sizes, int n_in,
                              void* d_out, int out_size, void* d_ws, size_t ws_size,
                              hipStream_t stream) {
  const float* img     = (const float*)d_in[0];
  const float* patch_w = (const float*)d_in[1];
  const float* patch_b = (const float*)d_in[2];
  const float* pos_emb = (const float*)d_in[3];
  const float* cls_tok = (const float*)d_in[4];
  const float* ln1_w   = (const float*)d_in[5];
  const float* ln1_b   = (const float*)d_in[6];
  const float* qkv_w   = (const float*)d_in[7];
  const float* out_w   = (const float*)d_in[8];
  const float* out_b   = (const float*)d_in[9];
  const float* ln2_w   = (const float*)d_in[10];
  const float* ln2_b   = (const float*)d_in[11];
  const float* ff1_w   = (const float*)d_in[12];
  const float* ff1_b   = (const float*)d_in[13];
  const float* ff2_w   = (const float*)d_in[14];
  const float* ff2_b   = (const float*)d_in[15];
  const float* hln_w   = (const float*)d_in[16];
  const float* hln_b   = (const float*)d_in[17];
  const float* head_w  = (const float*)d_in[18];
  const float* head_b  = (const float*)d_in[19];
  float* outp = (float*)d_out;

  char* wsp = (char*)d_ws;
  auto alloc = [&](size_t bytes) {
    char* p = wsp;
    wsp += (bytes + 255) & ~(size_t)255;
    return p;
  };
  float*  x    = (float*) alloc((size_t)9232 * 768 * 4);
  ushort* h    = (ushort*)alloc((size_t)9232 * 768 * 2);
  ushort* qkvb = (ushort*)alloc((size_t)9232 * 2304 * 2);
  ushort* mlp  = (ushort*)alloc((size_t)9232 * 3072 * 2);
  ushort* wq   = (ushort*)alloc((size_t)768 * 2304 * 2);
  ushort* wo   = (ushort*)alloc((size_t)768 * 768 * 2);
  ushort* w1   = (ushort*)alloc((size_t)768 * 3072 * 2);
  ushort* w2   = (ushort*)alloc((size_t)3072 * 768 * 2);
  ushort* apatch = mlp;
  ushort* wpatch = wq;

  // ---- patch embedding ----
  convt_kernel<<<dim3(24, 24), 256, 0, stream>>>(patch_w, wpatch, 768, 768);
  im2col_kernel<<<27648, 256, 0, stream>>>(img, apatch);
  gemmP_kernel<EPI_PATCH><<<72 * 6, 256, 0, stream>>>(
      apatch, wpatch, patch_b, pos_emb, x, 9216, 768, 768, 72);
  clspos_kernel<<<48, 256, 0, stream>>>(cls_tok, pos_emb, x);

  // ---- transformer layers ----
  for (int l = 0; l < 12; ++l) {
    ln_kernel<<<9232, 64, 0, stream>>>(x, ln1_w + l * 768, ln1_b + l * 768, h);
    convt_kernel<<<dim3(24, 72), 256, 0, stream>>>(qkv_w + (size_t)l * 768 * 2304, wq, 768, 2304);
    gemmP_kernel<EPI_BF16><<<73 * 18, 256, 0, stream>>>(
        h, wq, nullptr, nullptr, qkvb, 9232, 2304, 768, 73);
    attn_kernel<<<dim3(192, 10), 256, 0, stream>>>(qkvb, h);  // o -> h
    convt_kernel<<<dim3(24, 24), 256, 0, stream>>>(out_w + (size_t)l * 768 * 768, wo, 768, 768);
    gemmP_kernel<EPI_RES_F32><<<73 * 6, 256, 0, stream>>>(
        h, wo, out_b + l * 768, x, x, 9232, 768, 768, 73);
    ln_kernel<<<9232, 64, 0, stream>>>(x, ln2_w + l * 768, ln2_b + l * 768, h);
    convt_kernel<<<dim3(24, 96), 256, 0, stream>>>(ff1_w + (size_t)l * 768 * 3072, w1, 768, 3072);
    gemmP_kernel<EPI_GELU_BF16><<<73 * 24, 256, 0, stream>>>(
        h, w1, ff1_b + l * 3072, nullptr, mlp, 9232, 3072, 768, 73);
    convt_kernel<<<dim3(96, 24), 256, 0, stream>>>(ff2_w + (size_t)l * 3072 * 768, w2, 3072, 768);
    gemmP_kernel<EPI_RES_F32><<<73 * 6, 256, 0, stream>>>(
        mlp, w2, ff2_b + l * 768, x, x, 9232, 768, 3072, 73);
  }

  // ---- classification head ----
  head_kernel<<<dim3(16, 4), 256, 0, stream>>>(x, hln_w, hln_b, head_w, head_b, outp);
}

// Round 8
// 4240.055 us; speedup vs baseline: 1.0578x; 1.0578x over previous
//
#include <hip/hip_runtime.h>
#include <cstdint>

// ============================================================================
// ViT forward, MI355X round 8.
//   R8 changes vs R7:
//   - Revert qkv/ff1 to gemm8 (256^2, 8-phase): R7 A/B showed gemmP-ff1
//     117us/373TF/173MB-fetch vs gemm8-ff1 99us/442TF/91MB-fetch. The 256^2
//     tile halves HBM traffic; gemmP keeps proj/ff2/patch (N=768 grids).
//   - wconv_kernel: the 4 per-layer weight transposes fused into ONE launch
//     (48 -> 12 convt launches, ~350us of small-kernel+gap time -> ~120us).
// ============================================================================

typedef __attribute__((ext_vector_type(8))) short bf16x8;
typedef __attribute__((ext_vector_type(4))) float f32x4;

#define NTOK 577

__device__ __forceinline__ ushort f2bf(float f) {
  union { float f; unsigned int u; } x; x.f = f;
  unsigned int r = x.u + 0x7fffu + ((x.u >> 16) & 1u);  // RNE
  return (ushort)(r >> 16);
}

__device__ __forceinline__ void gload_lds16(const ushort* g, ushort* l) {
  __builtin_amdgcn_global_load_lds(
      (const __attribute__((address_space(1))) unsigned int*)g,
      (__attribute__((address_space(3))) unsigned int*)l, 16, 0, 0);
}

#define VMCNT4 asm volatile("s_waitcnt vmcnt(4)" ::: "memory")
#define VMCNT2 asm volatile("s_waitcnt vmcnt(2)" ::: "memory")
#define VMCNT0 asm volatile("s_waitcnt vmcnt(0)" ::: "memory")
#define LGKM0  asm volatile("s_waitcnt lgkmcnt(0)" ::: "memory")
#define SCHED0 __builtin_amdgcn_sched_barrier(0)
#define BARRIER __builtin_amdgcn_s_barrier()

// rotation swizzle: logical 16B-granule at row -> physical granule rotation
__device__ __forceinline__ int gsw(int row) {
  return (row & 7) + 2 * ((row >> 4) & 3);
}

// ---------------------------------------------------------------------------
// 32x32 transpose tile body: W[K][N] f32 -> Wt[N][K] bf16
// ---------------------------------------------------------------------------
__device__ __forceinline__ void transpose_tile(const float* __restrict__ W,
                                               ushort* __restrict__ Wt,
                                               int K, int N, int kb, int nb,
                                               int tx, int ty, float t[32][33]) {
#pragma unroll
  for (int i = 0; i < 32; i += 8)
    t[ty + i][tx] = W[(size_t)(kb + ty + i) * N + (nb + tx)];
  __syncthreads();
#pragma unroll
  for (int i = 0; i < 32; i += 8)
    Wt[(size_t)(nb + ty + i) * K + (kb + tx)] = f2bf(t[tx][ty + i]);
}

// standalone (patch embedding weight)
__global__ __launch_bounds__(256) void convt_kernel(const float* __restrict__ W,
                                                    ushort* __restrict__ Wt,
                                                    int K, int N) {
  __shared__ float t[32][33];
  transpose_tile(W, Wt, K, N, blockIdx.x * 32, blockIdx.y * 32,
                 threadIdx.x & 31, threadIdx.x >> 5, t);
}

// fused per-layer: qkv_w, out_w, ff1_w, ff2_w in one launch (6912 blocks)
__global__ __launch_bounds__(256) void wconv_kernel(
    const float* __restrict__ qkv_w, const float* __restrict__ out_w,
    const float* __restrict__ ff1_w, const float* __restrict__ ff2_w,
    ushort* __restrict__ wq, ushort* __restrict__ wo,
    ushort* __restrict__ w1, ushort* __restrict__ w2) {
  __shared__ float t[32][33];
  const int tx = threadIdx.x & 31, ty = threadIdx.x >> 5;
  int bx = blockIdx.x;
  if (bx < 1728) {          // qkv: 768 x 2304 (24 x 72 tiles)
    transpose_tile(qkv_w, wq, 768, 2304, (bx % 24) * 32, (bx / 24) * 32, tx, ty, t);
  } else if (bx < 2304) {   // out: 768 x 768 (24 x 24)
    bx -= 1728;
    transpose_tile(out_w, wo, 768, 768, (bx % 24) * 32, (bx / 24) * 32, tx, ty, t);
  } else if (bx < 4608) {   // ff1: 768 x 3072 (24 x 96)
    bx -= 2304;
    transpose_tile(ff1_w, w1, 768, 3072, (bx % 24) * 32, (bx / 24) * 32, tx, ty, t);
  } else {                  // ff2: 3072 x 768 (96 x 24)
    bx -= 4608;
    transpose_tile(ff2_w, w2, 3072, 768, (bx % 96) * 32, (bx / 96) * 32, tx, ty, t);
  }
}

// ---------------------------------------------------------------------------
// im2col: img (B,3,384,384) f32 -> Apatch (9216 x 768) bf16
// ---------------------------------------------------------------------------
__global__ __launch_bounds__(256) void im2col_kernel(const float* __restrict__ img,
                                                     ushort* __restrict__ Ap) {
  const int idx = blockIdx.x * 256 + threadIdx.x;  // 9216*768 exactly
  const int j = idx % 768;
  const int m = idx / 768;
  const int c = j % 3;
  const int q = j / 3;
  const int px = q & 15, py = q >> 4;
  const int b = m / 576, p = m % 576;
  const int gy = p / 24, gx = p % 24;
  const float v = img[((size_t)(b * 3 + c) * 384 + (gy * 16 + py)) * 384 + (gx * 16 + px)];
  Ap[idx] = f2bf(v);
}

__global__ void clspos_kernel(const float* __restrict__ cls_tok,
                              const float* __restrict__ pos,
                              float* __restrict__ x) {
  const int i = blockIdx.x * 256 + threadIdx.x;  // 16*768
  const int b = i / 768, d = i % 768;
  x[(size_t)b * NTOK * 768 + d] = cls_tok[d] + pos[d];
}

// ---------------------------------------------------------------------------
// LayerNorm row kernel: x f32 row (768) -> bf16 out row. 1 wave per row.
// ---------------------------------------------------------------------------
__global__ __launch_bounds__(64) void ln_kernel(const float* __restrict__ x,
                                                const float* __restrict__ w,
                                                const float* __restrict__ bb,
                                                ushort* __restrict__ out) {
  const int row = blockIdx.x, lane = threadIdx.x;
  const float4* xr = reinterpret_cast<const float4*>(x + (size_t)row * 768);
  const float4 v0 = xr[lane], v1 = xr[lane + 64], v2 = xr[lane + 128];
  float vals[12] = {v0.x, v0.y, v0.z, v0.w, v1.x, v1.y, v1.z, v1.w,
                    v2.x, v2.y, v2.z, v2.w};
  float s = 0.f;
#pragma unroll
  for (int i = 0; i < 12; ++i) s += vals[i];
#pragma unroll
  for (int o = 32; o; o >>= 1) s += __shfl_xor(s, o);
  const float mu = s * (1.0f / 768.0f);
  float q = 0.f;
#pragma unroll
  for (int i = 0; i < 12; ++i) { const float d = vals[i] - mu; q += d * d; }
#pragma unroll
  for (int o = 32; o; o >>= 1) q += __shfl_xor(q, o);
  const float rstd = rsqrtf(q * (1.0f / 768.0f) + 1e-5f);
  const float4* w4 = reinterpret_cast<const float4*>(w);
  const float4* b4 = reinterpret_cast<const float4*>(bb);
  ushort* orow = out + (size_t)row * 768;
#pragma unroll
  for (int ch = 0; ch < 3; ++ch) {
    const float4 wv = w4[lane + ch * 64];
    const float4 bv = b4[lane + ch * 64];
    ushort4 u;
    u.x = f2bf((vals[ch * 4 + 0] - mu) * rstd * wv.x + bv.x);
    u.y = f2bf((vals[ch * 4 + 1] - mu) * rstd * wv.y + bv.y);
    u.z = f2bf((vals[ch * 4 + 2] - mu) * rstd * wv.z + bv.z);
    u.w = f2bf((vals[ch * 4 + 3] - mu) * rstd * wv.w + bv.w);
    *reinterpret_cast<ushort4*>(orow + ch * 256 + lane * 4) = u;
  }
}

// ---------------------------------------------------------------------------
// Epilogue IDs
// ---------------------------------------------------------------------------
constexpr int EPI_BF16 = 0;       // C = acc                     -> bf16
constexpr int EPI_GELU_BF16 = 1;  // C = gelu(acc + bias)        -> bf16
constexpr int EPI_RES_F32 = 2;    // C = acc + bias + extra[r,c] -> f32
constexpr int EPI_PATCH = 3;      // x[row+b+1] = acc + patch_b + pos[p+1]

// ---------------------------------------------------------------------------
// 256x256 8-phase MFMA GEMM (qkv / ff1): traffic-optimal for K=768, N>=2304.
// ---------------------------------------------------------------------------
template <int EPI>
__global__ __launch_bounds__(512, 2) void gemm8_kernel(
    const ushort* __restrict__ A, const ushort* __restrict__ Bt,
    const float* __restrict__ bias, void* __restrict__ Cptr,
    int M, int N, int K, int mt) {
  __shared__ ushort lds[2][2][16384];  // [buf][A/B][row*64 + phys]

  const int nwg = gridDim.x;
  const int orig = blockIdx.x;
  const int q8 = nwg >> 3, r8 = nwg & 7, xcd = orig & 7, sidx = orig >> 3;
  const int wg = (xcd < r8 ? xcd * (q8 + 1) : r8 * (q8 + 1) + (xcd - r8) * q8) + sidx;
  const int tileM = (wg % mt) * 256;
  const int tileN = (wg / mt) * 256;

  const int tid = threadIdx.x;
  const int wave = tid >> 6, lane = tid & 63;
  const int wm = wave >> 2, wn = wave & 3;
  const int lr = lane & 15, lg = lane >> 4;

  f32x4 acc[8][4];
#pragma unroll
  for (int i = 0; i < 8; ++i)
#pragma unroll
    for (int j = 0; j < 4; ++j) acc[i][j] = (f32x4){0.f, 0.f, 0.f, 0.f};

  int rsA[2][2], rsB[2][2];
  const ushort* pA[2][2];
  const ushort* pB[2][2];
#pragma unroll
  for (int h = 0; h < 2; ++h)
#pragma unroll
    for (int g = 0; g < 2; ++g) {
      const int c = wave * 2 + g;
      {
        const int rowst = h * 64 + ((c >> 3) << 7) + ((c & 7) << 3);
        rsA[h][g] = rowst;
        const int row = rowst + (lane >> 3);
        const int lgr = ((lane & 7) - gsw(row)) & 7;
        pA[h][g] = A + (size_t)(tileM + row) * K + lgr * 8;
      }
      {
        const int rowst = h * 32 + ((c >> 2) << 6) + ((c & 3) << 3);
        rsB[h][g] = rowst;
        const int row = rowst + (lane >> 3);
        const int lgr = ((lane & 7) - gsw(row)) & 7;
        pB[h][g] = Bt + (size_t)(tileN + row) * K + lgr * 8;
      }
    }

#define STAGE_A(h, buf, k1)                                   \
  gload_lds16(pA[h][0] + (k1), &lds[buf][0][rsA[h][0] * 64]); \
  gload_lds16(pA[h][1] + (k1), &lds[buf][0][rsA[h][1] * 64]);
#define STAGE_B(h, buf, k1)                                   \
  gload_lds16(pB[h][0] + (k1), &lds[buf][1][rsB[h][0] * 64]); \
  gload_lds16(pB[h][1] + (k1), &lds[buf][1][rsB[h][1] * 64]);

  bf16x8 areg[8], breg[4];
#define LDA8(h, buf)                                                          \
  {                                                                           \
    const ushort* base = &lds[buf][0][0];                                     \
    _Pragma("unroll") for (int mf = 0; mf < 4; ++mf) {                        \
      const int row = wm * 128 + (h) * 64 + mf * 16 + lr;                     \
      _Pragma("unroll") for (int ks = 0; ks < 2; ++ks) {                      \
        const int pg = (ks * 4 + lg + (lr & 7) + 2 * mf) & 7;                 \
        areg[mf * 2 + ks] =                                                   \
            *reinterpret_cast<const bf16x8*>(&base[row * 64 + pg * 8]);       \
      }                                                                       \
    }                                                                         \
  }
#define LDB4(q, buf)                                                          \
  {                                                                           \
    const ushort* base = &lds[buf][1][0];                                     \
    _Pragma("unroll") for (int nf = 0; nf < 2; ++nf) {                        \
      const int row = wn * 64 + (q) * 32 + nf * 16 + lr;                      \
      _Pragma("unroll") for (int ks = 0; ks < 2; ++ks) {                      \
        const int pg = (ks * 4 + lg + (lr & 7) + 2 * (((q)*2 + nf) & 3)) & 7; \
        breg[nf * 2 + ks] =                                                   \
            *reinterpret_cast<const bf16x8*>(&base[row * 64 + pg * 8]);       \
      }                                                                       \
    }                                                                         \
  }
#define MFMA16(h, q)                                                        \
  __builtin_amdgcn_s_setprio(1);                                            \
  _Pragma("unroll") for (int mf = 0; mf < 4; ++mf)                          \
      _Pragma("unroll") for (int nf = 0; nf < 2; ++nf)                      \
          _Pragma("unroll") for (int ks = 0; ks < 2; ++ks)                  \
              acc[(h)*4 + mf][(q)*2 + nf] =                                 \
                  __builtin_amdgcn_mfma_f32_16x16x32_bf16(                  \
                      areg[mf * 2 + ks], breg[nf * 2 + ks],                 \
                      acc[(h)*4 + mf][(q)*2 + nf], 0, 0, 0);                \
  __builtin_amdgcn_s_setprio(0);

  STAGE_A(0, 0, 0);
  STAGE_B(0, 0, 0);
  STAGE_A(1, 0, 0);
  STAGE_B(1, 0, 0);

  const int NT = K >> 6;
  for (int t = 0; t < NT - 1; ++t) {
    const int cb = t & 1, nb = (t + 1) & 1;
    const int k1 = (t + 1) * 64;
    VMCNT4; SCHED0;
    BARRIER;
    LDA8(0, cb);
    LDB4(0, cb);
    STAGE_A(0, nb, k1);
    LGKM0; SCHED0;
    MFMA16(0, 0);
    VMCNT4; SCHED0;
    BARRIER;
    LDA8(1, cb);
    STAGE_B(0, nb, k1);
    LGKM0; SCHED0;
    MFMA16(1, 0);
    VMCNT4; SCHED0;
    BARRIER;
    LDB4(1, cb);
    STAGE_A(1, nb, k1);
    LGKM0; SCHED0;
    MFMA16(1, 1);
    BARRIER;
    LDA8(0, cb);
    STAGE_B(1, nb, k1);
    LGKM0; SCHED0;
    MFMA16(0, 1);
  }

  {  // peeled last K-tile with drain waits (race-fix, R4)
    const int cb = (NT - 1) & 1;
    VMCNT4; SCHED0;
    BARRIER;
    LDA8(0, cb);
    LDB4(0, cb);
    LGKM0; SCHED0;
    MFMA16(0, 0);
    VMCNT2; SCHED0;
    BARRIER;
    LDA8(1, cb);
    LGKM0; SCHED0;
    MFMA16(1, 0);
    VMCNT0; SCHED0;
    BARRIER;
    LDB4(1, cb);
    LGKM0; SCHED0;
    MFMA16(1, 1);
    BARRIER;
    LDA8(0, cb);
    LGKM0; SCHED0;
    MFMA16(0, 1);
  }

#pragma unroll
  for (int am = 0; am < 8; ++am) {
#pragma unroll
    for (int r = 0; r < 4; ++r) {
      const int row = tileM + wm * 128 + (am >> 2) * 64 + (am & 3) * 16 + lg * 4 + r;
      if (row >= M) continue;
#pragma unroll
      for (int an = 0; an < 4; ++an) {
        const int col = tileN + wn * 64 + (an >> 1) * 32 + (an & 1) * 16 + lr;
        float v = acc[am][an][r];
        if constexpr (EPI == EPI_BF16) {
          reinterpret_cast<ushort*>(Cptr)[(size_t)row * N + col] = f2bf(v);
        } else {  // EPI_GELU_BF16
          v += bias[col];
          v = 0.5f * v * (1.0f + erff(v * 0.70710678118654752440f));
          reinterpret_cast<ushort*>(Cptr)[(size_t)row * N + col] = f2bf(v);
        }
      }
    }
  }
#undef STAGE_A
#undef STAGE_B
#undef LDA8
#undef LDB4
#undef MFMA16
}

// ---------------------------------------------------------------------------
// gemmP: 128x128, BK=64, dbuf 64 KiB (2 blocks/CU). For patch / proj / ff2.
// ---------------------------------------------------------------------------
template <int EPI>
__global__ __launch_bounds__(256) void gemmP_kernel(
    const ushort* __restrict__ A, const ushort* __restrict__ Bt,
    const float* __restrict__ bias, const float* __restrict__ extra,
    void* __restrict__ Cptr, int M, int N, int K, int mt) {
  __shared__ ushort ldsA[2][128 * 64];
  __shared__ ushort ldsB[2][128 * 64];

  const int nwg = gridDim.x;
  const int orig = blockIdx.x;
  const int q8 = nwg >> 3, r8 = nwg & 7, xcd = orig & 7, sidx = orig >> 3;
  const int wg = (xcd < r8 ? xcd * (q8 + 1) : r8 * (q8 + 1) + (xcd - r8) * q8) + sidx;
  const int tileM = (wg % mt) * 128;
  const int tileN = (wg / mt) * 128;

  const int tid = threadIdx.x;
  const int wave = tid >> 6, lane = tid & 63;
  const int wm = wave >> 1, wn = wave & 1;
  const int lr = lane & 15, lg = lane >> 4;

  f32x4 acc[4][4];
#pragma unroll
  for (int m = 0; m < 4; ++m)
#pragma unroll
    for (int n = 0; n < 4; ++n) acc[m][n] = (f32x4){0.f, 0.f, 0.f, 0.f};

  const ushort* pA[4];
  const ushort* pB[4];
  int dst[4];
#pragma unroll
  for (int i = 0; i < 4; ++i) {
    const int c = wave * 4 + i;
    const int rowst = c * 8;
    dst[i] = rowst * 64;
    const int row = rowst + (lane >> 3);
    const int lgr = ((lane & 7) - gsw(row)) & 7;
    pA[i] = A + (size_t)(tileM + row) * K + lgr * 8;
    pB[i] = Bt + (size_t)(tileN + row) * K + lgr * 8;
  }

#define PSTAGE(buf, kk)                              \
  _Pragma("unroll") for (int i = 0; i < 4; ++i)      \
      gload_lds16(pA[i] + (kk), &ldsA[buf][dst[i]]); \
  _Pragma("unroll") for (int i = 0; i < 4; ++i)      \
      gload_lds16(pB[i] + (kk), &ldsB[buf][dst[i]]);

  PSTAGE(0, 0);

  const int NT = K >> 6;
  int cb = 0;
  for (int t = 0; t < NT; ++t) {
    VMCNT0; SCHED0;
    BARRIER;
    if (t + 1 < NT) { PSTAGE(cb ^ 1, (t + 1) * 64); }
    bf16x8 a[8], b[8];
#pragma unroll
    for (int mf = 0; mf < 4; ++mf) {
      const int row = wm * 64 + mf * 16 + lr;
#pragma unroll
      for (int ks = 0; ks < 2; ++ks) {
        const int pg = (ks * 4 + lg + (lr & 7) + 2 * mf) & 7;
        a[mf * 2 + ks] = *reinterpret_cast<const bf16x8*>(&ldsA[cb][row * 64 + pg * 8]);
      }
    }
#pragma unroll
    for (int nf = 0; nf < 4; ++nf) {
      const int row = wn * 64 + nf * 16 + lr;
#pragma unroll
      for (int ks = 0; ks < 2; ++ks) {
        const int pg = (ks * 4 + lg + (lr & 7) + 2 * nf) & 7;
        b[nf * 2 + ks] = *reinterpret_cast<const bf16x8*>(&ldsB[cb][row * 64 + pg * 8]);
      }
    }
    LGKM0; SCHED0;
    __builtin_amdgcn_s_setprio(1);
#pragma unroll
    for (int mf = 0; mf < 4; ++mf)
#pragma unroll
      for (int nf = 0; nf < 4; ++nf)
#pragma unroll
        for (int ks = 0; ks < 2; ++ks)
          acc[mf][nf] = __builtin_amdgcn_mfma_f32_16x16x32_bf16(
              a[mf * 2 + ks], b[nf * 2 + ks], acc[mf][nf], 0, 0, 0);
    __builtin_amdgcn_s_setprio(0);
    cb ^= 1;
  }

#pragma unroll
  for (int mf = 0; mf < 4; ++mf) {
#pragma unroll
    for (int r = 0; r < 4; ++r) {
      const int row = tileM + wm * 64 + mf * 16 + lg * 4 + r;
      if (row >= M) continue;
#pragma unroll
      for (int nf = 0; nf < 4; ++nf) {
        const int col = tileN + wn * 64 + nf * 16 + lr;
        float v = acc[mf][nf][r];
        if constexpr (EPI == EPI_BF16) {
          reinterpret_cast<ushort*>(Cptr)[(size_t)row * N + col] = f2bf(v);
        } else if constexpr (EPI == EPI_GELU_BF16) {
          v += bias[col];
          v = 0.5f * v * (1.0f + erff(v * 0.70710678118654752440f));
          reinterpret_cast<ushort*>(Cptr)[(size_t)row * N + col] = f2bf(v);
        } else if constexpr (EPI == EPI_RES_F32) {
          v += bias[col] + extra[(size_t)row * N + col];
          reinterpret_cast<float*>(Cptr)[(size_t)row * N + col] = v;
        } else {  // EPI_PATCH
          const int bb = row / 576;
          const int p = row - bb * 576;
          v += bias[col] + extra[(size_t)(p + 1) * 768 + col];
          reinterpret_cast<float*>(Cptr)[(size_t)(row + bb + 1) * 768 + col] = v;
        }
      }
    }
  }
#undef PSTAGE
}

// ---------------------------------------------------------------------------
// MFMA flash attention with rotation-swizzled LDS. Unchanged.
// ---------------------------------------------------------------------------
__global__ __launch_bounds__(256) void attn_kernel(const ushort* __restrict__ qkv,
                                                   ushort* __restrict__ o) {
  __shared__ ushort sK[64 * 64];
  __shared__ ushort sVt[64 * 64];
  __shared__ ushort sP[4][16 * 72];
  const int bh = blockIdx.x;
  const int b = bh / 12, hh = bh % 12;
  const int q0 = blockIdx.y * 64;
  const int tid = threadIdx.x;
  const int wave = tid >> 6, lane = tid & 63;
  const int lr = lane & 15;
  const int lg = lane >> 4;
  const ushort* base = qkv + (size_t)b * NTOK * 2304 + hh * 64;
  const float SC = 0.03608439182435161f;  // 768^-0.5

  bf16x8 qf[2];
  {
    const int qrow = q0 + wave * 16 + lr;
    if (qrow < NTOK) {
      const ushort* qp = base + (size_t)qrow * 2304 + lg * 8;
      qf[0] = *reinterpret_cast<const bf16x8*>(qp);
      qf[1] = *reinterpret_cast<const bf16x8*>(qp + 32);
    } else {
      qf[0] = (bf16x8){0, 0, 0, 0, 0, 0, 0, 0};
      qf[1] = qf[0];
    }
  }

  float mst[4], lst[4];
  f32x4 oacc[4];
#pragma unroll
  for (int i = 0; i < 4; ++i) {
    mst[i] = -1e30f; lst[i] = 0.f;
    oacc[i] = (f32x4){0.f, 0.f, 0.f, 0.f};
  }

  const int skey = tid >> 2;
  const int sc4 = tid & 3;
  const int gswk = gsw(skey);

  for (int t0 = 0; t0 < NTOK; t0 += 64) {
    __syncthreads();
    {
      const int gk = t0 + skey;
      int4 k0v, k1v, v0v, v1v;
      if (gk < NTOK) {
        const int4* kp = reinterpret_cast<const int4*>(base + (size_t)gk * 2304 + 768 + sc4 * 16);
        k0v = kp[0]; k1v = kp[1];
        const int4* vp = reinterpret_cast<const int4*>(base + (size_t)gk * 2304 + 1536 + sc4 * 16);
        v0v = vp[0]; v1v = vp[1];
      } else {
        int4 z; z.x = z.y = z.z = z.w = 0;
        k0v = k1v = v0v = v1v = z;
      }
      *reinterpret_cast<int4*>(&sK[skey * 64 + (((2 * sc4 + 0) + gswk) & 7) * 8]) = k0v;
      *reinterpret_cast<int4*>(&sK[skey * 64 + (((2 * sc4 + 1) + gswk) & 7) * 8]) = k1v;
      const ushort* vs = reinterpret_cast<const ushort*>(&v0v);
      const ushort* vs2 = reinterpret_cast<const ushort*>(&v1v);
#pragma unroll
      for (int i = 0; i < 8; ++i) {
        const int d0 = sc4 * 16 + i;
        const int pg0 = ((skey >> 3) + gsw(d0)) & 7;
        sVt[d0 * 64 + pg0 * 8 + (skey & 7)] = vs[i];
        const int d1 = sc4 * 16 + 8 + i;
        const int pg1 = ((skey >> 3) + gsw(d1)) & 7;
        sVt[d1 * 64 + pg1 * 8 + (skey & 7)] = vs2[i];
      }
    }
    __syncthreads();

    f32x4 sacc[4];
#pragma unroll
    for (int n = 0; n < 4; ++n) sacc[n] = (f32x4){0.f, 0.f, 0.f, 0.f};
#pragma unroll
    for (int n = 0; n < 4; ++n) {
      const int row = n * 16 + lr;
      const int rot = (lr & 7) + 2 * n;
      const bf16x8 kf0 = *reinterpret_cast<const bf16x8*>(&sK[row * 64 + ((lg + rot) & 7) * 8]);
      const bf16x8 kf1 = *reinterpret_cast<const bf16x8*>(&sK[row * 64 + ((4 + lg + rot) & 7) * 8]);
      sacc[n] = __builtin_amdgcn_mfma_f32_16x16x32_bf16(qf[0], kf0, sacc[n], 0, 0, 0);
      sacc[n] = __builtin_amdgcn_mfma_f32_16x16x32_bf16(qf[1], kf1, sacc[n], 0, 0, 0);
    }

    float s[4][4], pm[4];
#pragma unroll
    for (int reg = 0; reg < 4; ++reg) pm[reg] = -1e30f;
#pragma unroll
    for (int n = 0; n < 4; ++n)
#pragma unroll
      for (int reg = 0; reg < 4; ++reg) {
        float v = sacc[n][reg] * SC;
        if (t0 + n * 16 + lr >= NTOK) v = -1e30f;
        s[n][reg] = v;
        pm[reg] = fmaxf(pm[reg], v);
      }
#pragma unroll
    for (int off = 1; off < 16; off <<= 1)
#pragma unroll
      for (int reg = 0; reg < 4; ++reg) pm[reg] = fmaxf(pm[reg], __shfl_xor(pm[reg], off));

    float al[4], rs[4];
#pragma unroll
    for (int reg = 0; reg < 4; ++reg) {
      const float mn = fmaxf(mst[reg], pm[reg]);
      al[reg] = __expf(mst[reg] - mn);
      mst[reg] = mn;
      rs[reg] = 0.f;
    }
#pragma unroll
    for (int n = 0; n < 4; ++n)
#pragma unroll
      for (int reg = 0; reg < 4; ++reg) {
        s[n][reg] = __expf(s[n][reg] - mst[reg]);
        rs[reg] += s[n][reg];
      }
#pragma unroll
    for (int off = 1; off < 16; off <<= 1)
#pragma unroll
      for (int reg = 0; reg < 4; ++reg) rs[reg] += __shfl_xor(rs[reg], off);
#pragma unroll
    for (int reg = 0; reg < 4; ++reg) {
      lst[reg] = lst[reg] * al[reg] + rs[reg];
#pragma unroll
      for (int n = 0; n < 4; ++n) oacc[n][reg] *= al[reg];
    }

#pragma unroll
    for (int n = 0; n < 4; ++n)
#pragma unroll
      for (int reg = 0; reg < 4; ++reg)
        sP[wave][(lg * 4 + reg) * 72 + n * 16 + lr] = f2bf(s[n][reg]);

    const bf16x8 pf0 = *reinterpret_cast<const bf16x8*>(&sP[wave][lr * 72 + lg * 8]);
    const bf16x8 pf1 = *reinterpret_cast<const bf16x8*>(&sP[wave][lr * 72 + 32 + lg * 8]);
#pragma unroll
    for (int n = 0; n < 4; ++n) {
      const int row = n * 16 + lr;
      const int rot = (lr & 7) + 2 * n;
      const bf16x8 vf0 = *reinterpret_cast<const bf16x8*>(&sVt[row * 64 + ((lg + rot) & 7) * 8]);
      const bf16x8 vf1 = *reinterpret_cast<const bf16x8*>(&sVt[row * 64 + ((4 + lg + rot) & 7) * 8]);
      oacc[n] = __builtin_amdgcn_mfma_f32_16x16x32_bf16(pf0, vf0, oacc[n], 0, 0, 0);
      oacc[n] = __builtin_amdgcn_mfma_f32_16x16x32_bf16(pf1, vf1, oacc[n], 0, 0, 0);
    }
  }

#pragma unroll
  for (int reg = 0; reg < 4; ++reg) {
    const int q = q0 + wave * 16 + lg * 4 + reg;
    if (q >= NTOK) continue;
    const float inv = 1.0f / lst[reg];
    ushort* op = o + (size_t)(b * NTOK + q) * 768 + hh * 64;
#pragma unroll
    for (int n = 0; n < 4; ++n) op[n * 16 + lr] = f2bf(oacc[n][reg] * inv);
  }
}

// ---------------------------------------------------------------------------
// Head: LN(cls rows) @ head_w (768x1000) + head_b -> out (16x1000) f32
// ---------------------------------------------------------------------------
__global__ __launch_bounds__(256) void head_kernel(const float* __restrict__ x,
                                                   const float* __restrict__ lw,
                                                   const float* __restrict__ lb,
                                                   const float* __restrict__ hw,
                                                   const float* __restrict__ hb,
                                                   float* __restrict__ out) {
  __shared__ float srow[768];
  __shared__ float sred[8];
  const int b = blockIdx.x, tid = threadIdx.x;
  const float* xr = x + (size_t)b * NTOK * 768;
  for (int i = tid; i < 768; i += 256) srow[i] = xr[i];
  __syncthreads();
  float part = srow[tid] + srow[tid + 256] + srow[tid + 512];
#pragma unroll
  for (int off = 32; off; off >>= 1) part += __shfl_xor(part, off);
  if ((tid & 63) == 0) sred[tid >> 6] = part;
  __syncthreads();
  const float mu = (sred[0] + sred[1] + sred[2] + sred[3]) * (1.0f / 768.0f);
  const float d0 = srow[tid] - mu, d1 = srow[tid + 256] - mu, d2 = srow[tid + 512] - mu;
  float vp = d0 * d0 + d1 * d1 + d2 * d2;
#pragma unroll
  for (int off = 32; off; off >>= 1) vp += __shfl_xor(vp, off);
  if ((tid & 63) == 0) sred[4 + (tid >> 6)] = vp;
  __syncthreads();
  const float rstd = rsqrtf((sred[4] + sred[5] + sred[6] + sred[7]) * (1.0f / 768.0f) + 1e-5f);
  for (int i = tid; i < 768; i += 256) srow[i] = (srow[i] - mu) * rstd * lw[i] + lb[i];
  __syncthreads();
  const int c = blockIdx.y * 250 + tid;
  if (tid < 250 && c < 1000) {
    float a = 0.f;
#pragma unroll 4
    for (int k = 0; k < 768; ++k) a += srow[k] * hw[(size_t)k * 1000 + c];
    out[b * 1000 + c] = a + hb[c];
  }
}

// ---------------------------------------------------------------------------
extern "C" void kernel_launch(void* const* d_in, const int* in_sizes, int n_in,
                              void* d_out, int out_size, void* d_ws, size_t ws_size,
                              hipStream_t stream) {
  const float* img     = (const float*)d_in[0];
  const float* patch_w = (const float*)d_in[1];
  const float* patch_b = (const float*)d_in[2];
  const float* pos_emb = (const float*)d_in[3];
  const float* cls_tok = (const float*)d_in[4];
  const float* ln1_w   = (const float*)d_in[5];
  const float* ln1_b   = (const float*)d_in[6];
  const float* qkv_w   = (const float*)d_in[7];
  const float* out_w   = (const float*)d_in[8];
  const float* out_b   = (const float*)d_in[9];
  const float* ln2_w   = (const float*)d_in[10];
  const float* ln2_b   = (const float*)d_in[11];
  const float* ff1_w   = (const float*)d_in[12];
  const float* ff1_b   = (const float*)d_in[13];
  const float* ff2_w   = (const float*)d_in[14];
  const float* ff2_b   = (const float*)d_in[15];
  const float* hln_w   = (const float*)d_in[16];
  const float* hln_b   = (const float*)d_in[17];
  const float* head_w  = (const float*)d_in[18];
  const float* head_b  = (const float*)d_in[19];
  float* outp = (float*)d_out;

  char* wsp = (char*)d_ws;
  auto alloc = [&](size_t bytes) {
    char* p = wsp;
    wsp += (bytes + 255) & ~(size_t)255;
    return p;
  };
  float*  x    = (float*) alloc((size_t)9232 * 768 * 4);
  ushort* h    = (ushort*)alloc((size_t)9232 * 768 * 2);
  ushort* qkvb = (ushort*)alloc((size_t)9232 * 2304 * 2);
  ushort* mlp  = (ushort*)alloc((size_t)9232 * 3072 * 2);
  ushort* wq   = (ushort*)alloc((size_t)768 * 2304 * 2);
  ushort* wo   = (ushort*)alloc((size_t)768 * 768 * 2);
  ushort* w1   = (ushort*)alloc((size_t)768 * 3072 * 2);
  ushort* w2   = (ushort*)alloc((size_t)3072 * 768 * 2);
  ushort* apatch = mlp;
  ushort* wpatch = wq;

  // ---- patch embedding ----
  convt_kernel<<<dim3(24, 24), 256, 0, stream>>>(patch_w, wpatch, 768, 768);
  im2col_kernel<<<27648, 256, 0, stream>>>(img, apatch);
  gemmP_kernel<EPI_PATCH><<<72 * 6, 256, 0, stream>>>(
      apatch, wpatch, patch_b, pos_emb, x, 9216, 768, 768, 72);
  clspos_kernel<<<48, 256, 0, stream>>>(cls_tok, pos_emb, x);

  // ---- transformer layers ----
  for (int l = 0; l < 12; ++l) {
    wconv_kernel<<<6912, 256, 0, stream>>>(
        qkv_w + (size_t)l * 768 * 2304, out_w + (size_t)l * 768 * 768,
        ff1_w + (size_t)l * 768 * 3072, ff2_w + (size_t)l * 3072 * 768,
        wq, wo, w1, w2);
    ln_kernel<<<9232, 64, 0, stream>>>(x, ln1_w + l * 768, ln1_b + l * 768, h);
    gemm8_kernel<EPI_BF16><<<37 * 9, 512, 0, stream>>>(
        h, wq, nullptr, qkvb, 9232, 2304, 768, 37);
    attn_kernel<<<dim3(192, 10), 256, 0, stream>>>(qkvb, h);  // o -> h
    gemmP_kernel<EPI_RES_F32><<<73 * 6, 256, 0, stream>>>(
        h, wo, out_b + l * 768, x, x, 9232, 768, 768, 73);
    ln_kernel<<<9232, 64, 0, stream>>>(x, ln2_w + l * 768, ln2_b + l * 768, h);
    gemm8_kernel<EPI_GELU_BF16><<<37 * 12, 512, 0, stream>>>(
        h, w1, ff1_b + l * 3072, mlp, 9232, 3072, 768, 37);
    gemmP_kernel<EPI_RES_F32><<<73 * 6, 256, 0, stream>>>(
        mlp, w2, ff2_b + l * 768, x, x, 9232, 768, 3072, 73);
  }

  // ---- classification head ----
  head_kernel<<<dim3(16, 4), 256, 0, stream>>>(x, hln_w, hln_b, head_w, head_b, outp);
}

// Round 9
// 4171.217 us; speedup vs baseline: 1.0752x; 1.0165x over previous
//
#include <hip/hip_runtime.h>
#include <cstdint>

// ============================================================================
// ViT forward, MI355X round 9.
//   R9 changes vs R8:
//   - gemm8: N-fast block mapping (tileM = wg/nt, tileN = wg%nt). Each XCD's
//     contiguous chunk now covers an A-band (~2 MB, L2-resident, reused
//     12x/9x) and streams B once, instead of streaming all of A 1.5x.
//     Predicted FETCH_SIZE 91 -> ~60 MB on ff1.
//   - ln_kernel: 4 rows per 256-thread block (2308 blocks vs 9232 1-wave).
// ============================================================================

typedef __attribute__((ext_vector_type(8))) short bf16x8;
typedef __attribute__((ext_vector_type(4))) float f32x4;

#define NTOK 577

__device__ __forceinline__ ushort f2bf(float f) {
  union { float f; unsigned int u; } x; x.f = f;
  unsigned int r = x.u + 0x7fffu + ((x.u >> 16) & 1u);  // RNE
  return (ushort)(r >> 16);
}

__device__ __forceinline__ void gload_lds16(const ushort* g, ushort* l) {
  __builtin_amdgcn_global_load_lds(
      (const __attribute__((address_space(1))) unsigned int*)g,
      (__attribute__((address_space(3))) unsigned int*)l, 16, 0, 0);
}

#define VMCNT4 asm volatile("s_waitcnt vmcnt(4)" ::: "memory")
#define VMCNT2 asm volatile("s_waitcnt vmcnt(2)" ::: "memory")
#define VMCNT0 asm volatile("s_waitcnt vmcnt(0)" ::: "memory")
#define LGKM0  asm volatile("s_waitcnt lgkmcnt(0)" ::: "memory")
#define SCHED0 __builtin_amdgcn_sched_barrier(0)
#define BARRIER __builtin_amdgcn_s_barrier()

// rotation swizzle: logical 16B-granule at row -> physical granule rotation
__device__ __forceinline__ int gsw(int row) {
  return (row & 7) + 2 * ((row >> 4) & 3);
}

// ---------------------------------------------------------------------------
// 32x32 transpose tile body: W[K][N] f32 -> Wt[N][K] bf16
// ---------------------------------------------------------------------------
__device__ __forceinline__ void transpose_tile(const float* __restrict__ W,
                                               ushort* __restrict__ Wt,
                                               int K, int N, int kb, int nb,
                                               int tx, int ty, float t[32][33]) {
#pragma unroll
  for (int i = 0; i < 32; i += 8)
    t[ty + i][tx] = W[(size_t)(kb + ty + i) * N + (nb + tx)];
  __syncthreads();
#pragma unroll
  for (int i = 0; i < 32; i += 8)
    Wt[(size_t)(nb + ty + i) * K + (kb + tx)] = f2bf(t[tx][ty + i]);
}

// standalone (patch embedding weight)
__global__ __launch_bounds__(256) void convt_kernel(const float* __restrict__ W,
                                                    ushort* __restrict__ Wt,
                                                    int K, int N) {
  __shared__ float t[32][33];
  transpose_tile(W, Wt, K, N, blockIdx.x * 32, blockIdx.y * 32,
                 threadIdx.x & 31, threadIdx.x >> 5, t);
}

// fused per-layer: qkv_w, out_w, ff1_w, ff2_w in one launch (6912 blocks)
__global__ __launch_bounds__(256) void wconv_kernel(
    const float* __restrict__ qkv_w, const float* __restrict__ out_w,
    const float* __restrict__ ff1_w, const float* __restrict__ ff2_w,
    ushort* __restrict__ wq, ushort* __restrict__ wo,
    ushort* __restrict__ w1, ushort* __restrict__ w2) {
  __shared__ float t[32][33];
  const int tx = threadIdx.x & 31, ty = threadIdx.x >> 5;
  int bx = blockIdx.x;
  if (bx < 1728) {          // qkv: 768 x 2304 (24 x 72 tiles)
    transpose_tile(qkv_w, wq, 768, 2304, (bx % 24) * 32, (bx / 24) * 32, tx, ty, t);
  } else if (bx < 2304) {   // out: 768 x 768 (24 x 24)
    bx -= 1728;
    transpose_tile(out_w, wo, 768, 768, (bx % 24) * 32, (bx / 24) * 32, tx, ty, t);
  } else if (bx < 4608) {   // ff1: 768 x 3072 (24 x 96)
    bx -= 2304;
    transpose_tile(ff1_w, w1, 768, 3072, (bx % 24) * 32, (bx / 24) * 32, tx, ty, t);
  } else {                  // ff2: 3072 x 768 (96 x 24)
    bx -= 4608;
    transpose_tile(ff2_w, w2, 3072, 768, (bx % 96) * 32, (bx / 96) * 32, tx, ty, t);
  }
}

// ---------------------------------------------------------------------------
// im2col: img (B,3,384,384) f32 -> Apatch (9216 x 768) bf16
// ---------------------------------------------------------------------------
__global__ __launch_bounds__(256) void im2col_kernel(const float* __restrict__ img,
                                                     ushort* __restrict__ Ap) {
  const int idx = blockIdx.x * 256 + threadIdx.x;  // 9216*768 exactly
  const int j = idx % 768;
  const int m = idx / 768;
  const int c = j % 3;
  const int q = j / 3;
  const int px = q & 15, py = q >> 4;
  const int b = m / 576, p = m % 576;
  const int gy = p / 24, gx = p % 24;
  const float v = img[((size_t)(b * 3 + c) * 384 + (gy * 16 + py)) * 384 + (gx * 16 + px)];
  Ap[idx] = f2bf(v);
}

__global__ void clspos_kernel(const float* __restrict__ cls_tok,
                              const float* __restrict__ pos,
                              float* __restrict__ x) {
  const int i = blockIdx.x * 256 + threadIdx.x;  // 16*768
  const int b = i / 768, d = i % 768;
  x[(size_t)b * NTOK * 768 + d] = cls_tok[d] + pos[d];
}

// ---------------------------------------------------------------------------
// LayerNorm: 4 rows per 256-thread block (wave w -> row blockIdx*4 + w).
// ---------------------------------------------------------------------------
__global__ __launch_bounds__(256) void ln_kernel(const float* __restrict__ x,
                                                 const float* __restrict__ w,
                                                 const float* __restrict__ bb,
                                                 ushort* __restrict__ out) {
  const int wave = threadIdx.x >> 6, lane = threadIdx.x & 63;
  const int row = blockIdx.x * 4 + wave;
  const float4* xr = reinterpret_cast<const float4*>(x + (size_t)row * 768);
  const float4 v0 = xr[lane], v1 = xr[lane + 64], v2 = xr[lane + 128];
  float vals[12] = {v0.x, v0.y, v0.z, v0.w, v1.x, v1.y, v1.z, v1.w,
                    v2.x, v2.y, v2.z, v2.w};
  float s = 0.f;
#pragma unroll
  for (int i = 0; i < 12; ++i) s += vals[i];
#pragma unroll
  for (int o = 32; o; o >>= 1) s += __shfl_xor(s, o);
  const float mu = s * (1.0f / 768.0f);
  float q = 0.f;
#pragma unroll
  for (int i = 0; i < 12; ++i) { const float d = vals[i] - mu; q += d * d; }
#pragma unroll
  for (int o = 32; o; o >>= 1) q += __shfl_xor(q, o);
  const float rstd = rsqrtf(q * (1.0f / 768.0f) + 1e-5f);
  const float4* w4 = reinterpret_cast<const float4*>(w);
  const float4* b4 = reinterpret_cast<const float4*>(bb);
  ushort* orow = out + (size_t)row * 768;
#pragma unroll
  for (int ch = 0; ch < 3; ++ch) {
    const float4 wv = w4[lane + ch * 64];
    const float4 bv = b4[lane + ch * 64];
    ushort4 u;
    u.x = f2bf((vals[ch * 4 + 0] - mu) * rstd * wv.x + bv.x);
    u.y = f2bf((vals[ch * 4 + 1] - mu) * rstd * wv.y + bv.y);
    u.z = f2bf((vals[ch * 4 + 2] - mu) * rstd * wv.z + bv.z);
    u.w = f2bf((vals[ch * 4 + 3] - mu) * rstd * wv.w + bv.w);
    *reinterpret_cast<ushort4*>(orow + ch * 256 + lane * 4) = u;
  }
}

// ---------------------------------------------------------------------------
// Epilogue IDs
// ---------------------------------------------------------------------------
constexpr int EPI_BF16 = 0;       // C = acc                     -> bf16
constexpr int EPI_GELU_BF16 = 1;  // C = gelu(acc + bias)        -> bf16
constexpr int EPI_RES_F32 = 2;    // C = acc + bias + extra[r,c] -> f32
constexpr int EPI_PATCH = 3;      // x[row+b+1] = acc + patch_b + pos[p+1]

// ---------------------------------------------------------------------------
// 256x256 8-phase MFMA GEMM (qkv / ff1). N-FAST mapping: tileM = wg/nt,
// tileN = wg%nt -> each XCD chunk holds an L2-resident A-band reused across
// all N-tiles; B streams once per XCD.
// ---------------------------------------------------------------------------
template <int EPI>
__global__ __launch_bounds__(512, 2) void gemm8_kernel(
    const ushort* __restrict__ A, const ushort* __restrict__ Bt,
    const float* __restrict__ bias, void* __restrict__ Cptr,
    int M, int N, int K, int nt) {
  __shared__ ushort lds[2][2][16384];  // [buf][A/B][row*64 + phys]

  const int nwg = gridDim.x;
  const int orig = blockIdx.x;
  const int q8 = nwg >> 3, r8 = nwg & 7, xcd = orig & 7, sidx = orig >> 3;
  const int wg = (xcd < r8 ? xcd * (q8 + 1) : r8 * (q8 + 1) + (xcd - r8) * q8) + sidx;
  const int tileM = (wg / nt) * 256;   // slow: A-band per XCD chunk
  const int tileN = (wg % nt) * 256;   // fast: sweep N within the band

  const int tid = threadIdx.x;
  const int wave = tid >> 6, lane = tid & 63;
  const int wm = wave >> 2, wn = wave & 3;
  const int lr = lane & 15, lg = lane >> 4;

  f32x4 acc[8][4];
#pragma unroll
  for (int i = 0; i < 8; ++i)
#pragma unroll
    for (int j = 0; j < 4; ++j) acc[i][j] = (f32x4){0.f, 0.f, 0.f, 0.f};

  int rsA[2][2], rsB[2][2];
  const ushort* pA[2][2];
  const ushort* pB[2][2];
#pragma unroll
  for (int h = 0; h < 2; ++h)
#pragma unroll
    for (int g = 0; g < 2; ++g) {
      const int c = wave * 2 + g;
      {
        const int rowst = h * 64 + ((c >> 3) << 7) + ((c & 7) << 3);
        rsA[h][g] = rowst;
        const int row = rowst + (lane >> 3);
        const int lgr = ((lane & 7) - gsw(row)) & 7;
        pA[h][g] = A + (size_t)(tileM + row) * K + lgr * 8;
      }
      {
        const int rowst = h * 32 + ((c >> 2) << 6) + ((c & 3) << 3);
        rsB[h][g] = rowst;
        const int row = rowst + (lane >> 3);
        const int lgr = ((lane & 7) - gsw(row)) & 7;
        pB[h][g] = Bt + (size_t)(tileN + row) * K + lgr * 8;
      }
    }

#define STAGE_A(h, buf, k1)                                   \
  gload_lds16(pA[h][0] + (k1), &lds[buf][0][rsA[h][0] * 64]); \
  gload_lds16(pA[h][1] + (k1), &lds[buf][0][rsA[h][1] * 64]);
#define STAGE_B(h, buf, k1)                                   \
  gload_lds16(pB[h][0] + (k1), &lds[buf][1][rsB[h][0] * 64]); \
  gload_lds16(pB[h][1] + (k1), &lds[buf][1][rsB[h][1] * 64]);

  bf16x8 areg[8], breg[4];
#define LDA8(h, buf)                                                          \
  {                                                                           \
    const ushort* base = &lds[buf][0][0];                                     \
    _Pragma("unroll") for (int mf = 0; mf < 4; ++mf) {                        \
      const int row = wm * 128 + (h) * 64 + mf * 16 + lr;                     \
      _Pragma("unroll") for (int ks = 0; ks < 2; ++ks) {                      \
        const int pg = (ks * 4 + lg + (lr & 7) + 2 * mf) & 7;                 \
        areg[mf * 2 + ks] =                                                   \
            *reinterpret_cast<const bf16x8*>(&base[row * 64 + pg * 8]);       \
      }                                                                       \
    }                                                                         \
  }
#define LDB4(q, buf)                                                          \
  {                                                                           \
    const ushort* base = &lds[buf][1][0];                                     \
    _Pragma("unroll") for (int nf = 0; nf < 2; ++nf) {                        \
      const int row = wn * 64 + (q) * 32 + nf * 16 + lr;                      \
      _Pragma("unroll") for (int ks = 0; ks < 2; ++ks) {                      \
        const int pg = (ks * 4 + lg + (lr & 7) + 2 * (((q)*2 + nf) & 3)) & 7; \
        breg[nf * 2 + ks] =                                                   \
            *reinterpret_cast<const bf16x8*>(&base[row * 64 + pg * 8]);       \
      }                                                                       \
    }                                                                         \
  }
#define MFMA16(h, q)                                                        \
  __builtin_amdgcn_s_setprio(1);                                            \
  _Pragma("unroll") for (int mf = 0; mf < 4; ++mf)                          \
      _Pragma("unroll") for (int nf = 0; nf < 2; ++nf)                      \
          _Pragma("unroll") for (int ks = 0; ks < 2; ++ks)                  \
              acc[(h)*4 + mf][(q)*2 + nf] =                                 \
                  __builtin_amdgcn_mfma_f32_16x16x32_bf16(                  \
                      areg[mf * 2 + ks], breg[nf * 2 + ks],                 \
                      acc[(h)*4 + mf][(q)*2 + nf], 0, 0, 0);                \
  __builtin_amdgcn_s_setprio(0);

  STAGE_A(0, 0, 0);
  STAGE_B(0, 0, 0);
  STAGE_A(1, 0, 0);
  STAGE_B(1, 0, 0);

  const int NT = K >> 6;
  for (int t = 0; t < NT - 1; ++t) {
    const int cb = t & 1, nb = (t + 1) & 1;
    const int k1 = (t + 1) * 64;
    VMCNT4; SCHED0;
    BARRIER;
    LDA8(0, cb);
    LDB4(0, cb);
    STAGE_A(0, nb, k1);
    LGKM0; SCHED0;
    MFMA16(0, 0);
    VMCNT4; SCHED0;
    BARRIER;
    LDA8(1, cb);
    STAGE_B(0, nb, k1);
    LGKM0; SCHED0;
    MFMA16(1, 0);
    VMCNT4; SCHED0;
    BARRIER;
    LDB4(1, cb);
    STAGE_A(1, nb, k1);
    LGKM0; SCHED0;
    MFMA16(1, 1);
    BARRIER;
    LDA8(0, cb);
    STAGE_B(1, nb, k1);
    LGKM0; SCHED0;
    MFMA16(0, 1);
  }

  {  // peeled last K-tile with drain waits (race-fix, R4)
    const int cb = (NT - 1) & 1;
    VMCNT4; SCHED0;
    BARRIER;
    LDA8(0, cb);
    LDB4(0, cb);
    LGKM0; SCHED0;
    MFMA16(0, 0);
    VMCNT2; SCHED0;
    BARRIER;
    LDA8(1, cb);
    LGKM0; SCHED0;
    MFMA16(1, 0);
    VMCNT0; SCHED0;
    BARRIER;
    LDB4(1, cb);
    LGKM0; SCHED0;
    MFMA16(1, 1);
    BARRIER;
    LDA8(0, cb);
    LGKM0; SCHED0;
    MFMA16(0, 1);
  }

#pragma unroll
  for (int am = 0; am < 8; ++am) {
#pragma unroll
    for (int r = 0; r < 4; ++r) {
      const int row = tileM + wm * 128 + (am >> 2) * 64 + (am & 3) * 16 + lg * 4 + r;
      if (row >= M) continue;
#pragma unroll
      for (int an = 0; an < 4; ++an) {
        const int col = tileN + wn * 64 + (an >> 1) * 32 + (an & 1) * 16 + lr;
        float v = acc[am][an][r];
        if constexpr (EPI == EPI_BF16) {
          reinterpret_cast<ushort*>(Cptr)[(size_t)row * N + col] = f2bf(v);
        } else {  // EPI_GELU_BF16
          v += bias[col];
          v = 0.5f * v * (1.0f + erff(v * 0.70710678118654752440f));
          reinterpret_cast<ushort*>(Cptr)[(size_t)row * N + col] = f2bf(v);
        }
      }
    }
  }
#undef STAGE_A
#undef STAGE_B
#undef LDA8
#undef LDB4
#undef MFMA16
}

// ---------------------------------------------------------------------------
// gemmP: 128x128, BK=64, dbuf 64 KiB (2 blocks/CU). For patch / proj / ff2.
// M-fast mapping kept (N=768: B-panel is the small reusable operand).
// ---------------------------------------------------------------------------
template <int EPI>
__global__ __launch_bounds__(256) void gemmP_kernel(
    const ushort* __restrict__ A, const ushort* __restrict__ Bt,
    const float* __restrict__ bias, const float* __restrict__ extra,
    void* __restrict__ Cptr, int M, int N, int K, int mt) {
  __shared__ ushort ldsA[2][128 * 64];
  __shared__ ushort ldsB[2][128 * 64];

  const int nwg = gridDim.x;
  const int orig = blockIdx.x;
  const int q8 = nwg >> 3, r8 = nwg & 7, xcd = orig & 7, sidx = orig >> 3;
  const int wg = (xcd < r8 ? xcd * (q8 + 1) : r8 * (q8 + 1) + (xcd - r8) * q8) + sidx;
  const int tileM = (wg % mt) * 128;
  const int tileN = (wg / mt) * 128;

  const int tid = threadIdx.x;
  const int wave = tid >> 6, lane = tid & 63;
  const int wm = wave >> 1, wn = wave & 1;
  const int lr = lane & 15, lg = lane >> 4;

  f32x4 acc[4][4];
#pragma unroll
  for (int m = 0; m < 4; ++m)
#pragma unroll
    for (int n = 0; n < 4; ++n) acc[m][n] = (f32x4){0.f, 0.f, 0.f, 0.f};

  const ushort* pA[4];
  const ushort* pB[4];
  int dst[4];
#pragma unroll
  for (int i = 0; i < 4; ++i) {
    const int c = wave * 4 + i;
    const int rowst = c * 8;
    dst[i] = rowst * 64;
    const int row = rowst + (lane >> 3);
    const int lgr = ((lane & 7) - gsw(row)) & 7;
    pA[i] = A + (size_t)(tileM + row) * K + lgr * 8;
    pB[i] = Bt + (size_t)(tileN + row) * K + lgr * 8;
  }

#define PSTAGE(buf, kk)                              \
  _Pragma("unroll") for (int i = 0; i < 4; ++i)      \
      gload_lds16(pA[i] + (kk), &ldsA[buf][dst[i]]); \
  _Pragma("unroll") for (int i = 0; i < 4; ++i)      \
      gload_lds16(pB[i] + (kk), &ldsB[buf][dst[i]]);

  PSTAGE(0, 0);

  const int NT = K >> 6;
  int cb = 0;
  for (int t = 0; t < NT; ++t) {
    VMCNT0; SCHED0;
    BARRIER;
    if (t + 1 < NT) { PSTAGE(cb ^ 1, (t + 1) * 64); }
    bf16x8 a[8], b[8];
#pragma unroll
    for (int mf = 0; mf < 4; ++mf) {
      const int row = wm * 64 + mf * 16 + lr;
#pragma unroll
      for (int ks = 0; ks < 2; ++ks) {
        const int pg = (ks * 4 + lg + (lr & 7) + 2 * mf) & 7;
        a[mf * 2 + ks] = *reinterpret_cast<const bf16x8*>(&ldsA[cb][row * 64 + pg * 8]);
      }
    }
#pragma unroll
    for (int nf = 0; nf < 4; ++nf) {
      const int row = wn * 64 + nf * 16 + lr;
#pragma unroll
      for (int ks = 0; ks < 2; ++ks) {
        const int pg = (ks * 4 + lg + (lr & 7) + 2 * nf) & 7;
        b[nf * 2 + ks] = *reinterpret_cast<const bf16x8*>(&ldsB[cb][row * 64 + pg * 8]);
      }
    }
    LGKM0; SCHED0;
    __builtin_amdgcn_s_setprio(1);
#pragma unroll
    for (int mf = 0; mf < 4; ++mf)
#pragma unroll
      for (int nf = 0; nf < 4; ++nf)
#pragma unroll
        for (int ks = 0; ks < 2; ++ks)
          acc[mf][nf] = __builtin_amdgcn_mfma_f32_16x16x32_bf16(
              a[mf * 2 + ks], b[nf * 2 + ks], acc[mf][nf], 0, 0, 0);
    __builtin_amdgcn_s_setprio(0);
    cb ^= 1;
  }

#pragma unroll
  for (int mf = 0; mf < 4; ++mf) {
#pragma unroll
    for (int r = 0; r < 4; ++r) {
      const int row = tileM + wm * 64 + mf * 16 + lg * 4 + r;
      if (row >= M) continue;
#pragma unroll
      for (int nf = 0; nf < 4; ++nf) {
        const int col = tileN + wn * 64 + nf * 16 + lr;
        float v = acc[mf][nf][r];
        if constexpr (EPI == EPI_BF16) {
          reinterpret_cast<ushort*>(Cptr)[(size_t)row * N + col] = f2bf(v);
        } else if constexpr (EPI == EPI_GELU_BF16) {
          v += bias[col];
          v = 0.5f * v * (1.0f + erff(v * 0.70710678118654752440f));
          reinterpret_cast<ushort*>(Cptr)[(size_t)row * N + col] = f2bf(v);
        } else if constexpr (EPI == EPI_RES_F32) {
          v += bias[col] + extra[(size_t)row * N + col];
          reinterpret_cast<float*>(Cptr)[(size_t)row * N + col] = v;
        } else {  // EPI_PATCH
          const int bb = row / 576;
          const int p = row - bb * 576;
          v += bias[col] + extra[(size_t)(p + 1) * 768 + col];
          reinterpret_cast<float*>(Cptr)[(size_t)(row + bb + 1) * 768 + col] = v;
        }
      }
    }
  }
#undef PSTAGE
}

// ---------------------------------------------------------------------------
// MFMA flash attention with rotation-swizzled LDS. Unchanged.
// ---------------------------------------------------------------------------
__global__ __launch_bounds__(256) void attn_kernel(const ushort* __restrict__ qkv,
                                                   ushort* __restrict__ o) {
  __shared__ ushort sK[64 * 64];
  __shared__ ushort sVt[64 * 64];
  __shared__ ushort sP[4][16 * 72];
  const int bh = blockIdx.x;
  const int b = bh / 12, hh = bh % 12;
  const int q0 = blockIdx.y * 64;
  const int tid = threadIdx.x;
  const int wave = tid >> 6, lane = tid & 63;
  const int lr = lane & 15;
  const int lg = lane >> 4;
  const ushort* base = qkv + (size_t)b * NTOK * 2304 + hh * 64;
  const float SC = 0.03608439182435161f;  // 768^-0.5

  bf16x8 qf[2];
  {
    const int qrow = q0 + wave * 16 + lr;
    if (qrow < NTOK) {
      const ushort* qp = base + (size_t)qrow * 2304 + lg * 8;
      qf[0] = *reinterpret_cast<const bf16x8*>(qp);
      qf[1] = *reinterpret_cast<const bf16x8*>(qp + 32);
    } else {
      qf[0] = (bf16x8){0, 0, 0, 0, 0, 0, 0, 0};
      qf[1] = qf[0];
    }
  }

  float mst[4], lst[4];
  f32x4 oacc[4];
#pragma unroll
  for (int i = 0; i < 4; ++i) {
    mst[i] = -1e30f; lst[i] = 0.f;
    oacc[i] = (f32x4){0.f, 0.f, 0.f, 0.f};
  }

  const int skey = tid >> 2;
  const int sc4 = tid & 3;
  const int gswk = gsw(skey);

  for (int t0 = 0; t0 < NTOK; t0 += 64) {
    __syncthreads();
    {
      const int gk = t0 + skey;
      int4 k0v, k1v, v0v, v1v;
      if (gk < NTOK) {
        const int4* kp = reinterpret_cast<const int4*>(base + (size_t)gk * 2304 + 768 + sc4 * 16);
        k0v = kp[0]; k1v = kp[1];
        const int4* vp = reinterpret_cast<const int4*>(base + (size_t)gk * 2304 + 1536 + sc4 * 16);
        v0v = vp[0]; v1v = vp[1];
      } else {
        int4 z; z.x = z.y = z.z = z.w = 0;
        k0v = k1v = v0v = v1v = z;
      }
      *reinterpret_cast<int4*>(&sK[skey * 64 + (((2 * sc4 + 0) + gswk) & 7) * 8]) = k0v;
      *reinterpret_cast<int4*>(&sK[skey * 64 + (((2 * sc4 + 1) + gswk) & 7) * 8]) = k1v;
      const ushort* vs = reinterpret_cast<const ushort*>(&v0v);
      const ushort* vs2 = reinterpret_cast<const ushort*>(&v1v);
#pragma unroll
      for (int i = 0; i < 8; ++i) {
        const int d0 = sc4 * 16 + i;
        const int pg0 = ((skey >> 3) + gsw(d0)) & 7;
        sVt[d0 * 64 + pg0 * 8 + (skey & 7)] = vs[i];
        const int d1 = sc4 * 16 + 8 + i;
        const int pg1 = ((skey >> 3) + gsw(d1)) & 7;
        sVt[d1 * 64 + pg1 * 8 + (skey & 7)] = vs2[i];
      }
    }
    __syncthreads();

    f32x4 sacc[4];
#pragma unroll
    for (int n = 0; n < 4; ++n) sacc[n] = (f32x4){0.f, 0.f, 0.f, 0.f};
#pragma unroll
    for (int n = 0; n < 4; ++n) {
      const int row = n * 16 + lr;
      const int rot = (lr & 7) + 2 * n;
      const bf16x8 kf0 = *reinterpret_cast<const bf16x8*>(&sK[row * 64 + ((lg + rot) & 7) * 8]);
      const bf16x8 kf1 = *reinterpret_cast<const bf16x8*>(&sK[row * 64 + ((4 + lg + rot) & 7) * 8]);
      sacc[n] = __builtin_amdgcn_mfma_f32_16x16x32_bf16(qf[0], kf0, sacc[n], 0, 0, 0);
      sacc[n] = __builtin_amdgcn_mfma_f32_16x16x32_bf16(qf[1], kf1, sacc[n], 0, 0, 0);
    }

    float s[4][4], pm[4];
#pragma unroll
    for (int reg = 0; reg < 4; ++reg) pm[reg] = -1e30f;
#pragma unroll
    for (int n = 0; n < 4; ++n)
#pragma unroll
      for (int reg = 0; reg < 4; ++reg) {
        float v = sacc[n][reg] * SC;
        if (t0 + n * 16 + lr >= NTOK) v = -1e30f;
        s[n][reg] = v;
        pm[reg] = fmaxf(pm[reg], v);
      }
#pragma unroll
    for (int off = 1; off < 16; off <<= 1)
#pragma unroll
      for (int reg = 0; reg < 4; ++reg) pm[reg] = fmaxf(pm[reg], __shfl_xor(pm[reg], off));

    float al[4], rs[4];
#pragma unroll
    for (int reg = 0; reg < 4; ++reg) {
      const float mn = fmaxf(mst[reg], pm[reg]);
      al[reg] = __expf(mst[reg] - mn);
      mst[reg] = mn;
      rs[reg] = 0.f;
    }
#pragma unroll
    for (int n = 0; n < 4; ++n)
#pragma unroll
      for (int reg = 0; reg < 4; ++reg) {
        s[n][reg] = __expf(s[n][reg] - mst[reg]);
        rs[reg] += s[n][reg];
      }
#pragma unroll
    for (int off = 1; off < 16; off <<= 1)
#pragma unroll
      for (int reg = 0; reg < 4; ++reg) rs[reg] += __shfl_xor(rs[reg], off);
#pragma unroll
    for (int reg = 0; reg < 4; ++reg) {
      lst[reg] = lst[reg] * al[reg] + rs[reg];
#pragma unroll
      for (int n = 0; n < 4; ++n) oacc[n][reg] *= al[reg];
    }

#pragma unroll
    for (int n = 0; n < 4; ++n)
#pragma unroll
      for (int reg = 0; reg < 4; ++reg)
        sP[wave][(lg * 4 + reg) * 72 + n * 16 + lr] = f2bf(s[n][reg]);

    const bf16x8 pf0 = *reinterpret_cast<const bf16x8*>(&sP[wave][lr * 72 + lg * 8]);
    const bf16x8 pf1 = *reinterpret_cast<const bf16x8*>(&sP[wave][lr * 72 + 32 + lg * 8]);
#pragma unroll
    for (int n = 0; n < 4; ++n) {
      const int row = n * 16 + lr;
      const int rot = (lr & 7) + 2 * n;
      const bf16x8 vf0 = *reinterpret_cast<const bf16x8*>(&sVt[row * 64 + ((lg + rot) & 7) * 8]);
      const bf16x8 vf1 = *reinterpret_cast<const bf16x8*>(&sVt[row * 64 + ((4 + lg + rot) & 7) * 8]);
      oacc[n] = __builtin_amdgcn_mfma_f32_16x16x32_bf16(pf0, vf0, oacc[n], 0, 0, 0);
      oacc[n] = __builtin_amdgcn_mfma_f32_16x16x32_bf16(pf1, vf1, oacc[n], 0, 0, 0);
    }
  }

#pragma unroll
  for (int reg = 0; reg < 4; ++reg) {
    const int q = q0 + wave * 16 + lg * 4 + reg;
    if (q >= NTOK) continue;
    const float inv = 1.0f / lst[reg];
    ushort* op = o + (size_t)(b * NTOK + q) * 768 + hh * 64;
#pragma unroll
    for (int n = 0; n < 4; ++n) op[n * 16 + lr] = f2bf(oacc[n][reg] * inv);
  }
}

// ---------------------------------------------------------------------------
// Head: LN(cls rows) @ head_w (768x1000) + head_b -> out (16x1000) f32
// ---------------------------------------------------------------------------
__global__ __launch_bounds__(256) void head_kernel(const float* __restrict__ x,
                                                   const float* __restrict__ lw,
                                                   const float* __restrict__ lb,
                                                   const float* __restrict__ hw,
                                                   const float* __restrict__ hb,
                                                   float* __restrict__ out) {
  __shared__ float srow[768];
  __shared__ float sred[8];
  const int b = blockIdx.x, tid = threadIdx.x;
  const float* xr = x + (size_t)b * NTOK * 768;
  for (int i = tid; i < 768; i += 256) srow[i] = xr[i];
  __syncthreads();
  float part = srow[tid] + srow[tid + 256] + srow[tid + 512];
#pragma unroll
  for (int off = 32; off; off >>= 1) part += __shfl_xor(part, off);
  if ((tid & 63) == 0) sred[tid >> 6] = part;
  __syncthreads();
  const float mu = (sred[0] + sred[1] + sred[2] + sred[3]) * (1.0f / 768.0f);
  const float d0 = srow[tid] - mu, d1 = srow[tid + 256] - mu, d2 = srow[tid + 512] - mu;
  float vp = d0 * d0 + d1 * d1 + d2 * d2;
#pragma unroll
  for (int off = 32; off; off >>= 1) vp += __shfl_xor(vp, off);
  if ((tid & 63) == 0) sred[4 + (tid >> 6)] = vp;
  __syncthreads();
  const float rstd = rsqrtf((sred[4] + sred[5] + sred[6] + sred[7]) * (1.0f / 768.0f) + 1e-5f);
  for (int i = tid; i < 768; i += 256) srow[i] = (srow[i] - mu) * rstd * lw[i] + lb[i];
  __syncthreads();
  const int c = blockIdx.y * 250 + tid;
  if (tid < 250 && c < 1000) {
    float a = 0.f;
#pragma unroll 4
    for (int k = 0; k < 768; ++k) a += srow[k] * hw[(size_t)k * 1000 + c];
    out[b * 1000 + c] = a + hb[c];
  }
}

// ---------------------------------------------------------------------------
extern "C" void kernel_launch(void* const* d_in, const int* in_sizes, int n_in,
                              void* d_out, int out_size, void* d_ws, size_t ws_size,
                              hipStream_t stream) {
  const float* img     = (const float*)d_in[0];
  const float* patch_w = (const float*)d_in[1];
  const float* patch_b = (const float*)d_in[2];
  const float* pos_emb = (const float*)d_in[3];
  const float* cls_tok = (const float*)d_in[4];
  const float* ln1_w   = (const float*)d_in[5];
  const float* ln1_b   = (const float*)d_in[6];
  const float* qkv_w   = (const float*)d_in[7];
  const float* out_w   = (const float*)d_in[8];
  const float* out_b   = (const float*)d_in[9];
  const float* ln2_w   = (const float*)d_in[10];
  const float* ln2_b   = (const float*)d_in[11];
  const float* ff1_w   = (const float*)d_in[12];
  const float* ff1_b   = (const float*)d_in[13];
  const float* ff2_w   = (const float*)d_in[14];
  const float* ff2_b   = (const float*)d_in[15];
  const float* hln_w   = (const float*)d_in[16];
  const float* hln_b   = (const float*)d_in[17];
  const float* head_w  = (const float*)d_in[18];
  const float* head_b  = (const float*)d_in[19];
  float* outp = (float*)d_out;

  char* wsp = (char*)d_ws;
  auto alloc = [&](size_t bytes) {
    char* p = wsp;
    wsp += (bytes + 255) & ~(size_t)255;
    return p;
  };
  float*  x    = (float*) alloc((size_t)9232 * 768 * 4);
  ushort* h    = (ushort*)alloc((size_t)9232 * 768 * 2);
  ushort* qkvb = (ushort*)alloc((size_t)9232 * 2304 * 2);
  ushort* mlp  = (ushort*)alloc((size_t)9232 * 3072 * 2);
  ushort* wq   = (ushort*)alloc((size_t)768 * 2304 * 2);
  ushort* wo   = (ushort*)alloc((size_t)768 * 768 * 2);
  ushort* w1   = (ushort*)alloc((size_t)768 * 3072 * 2);
  ushort* w2   = (ushort*)alloc((size_t)3072 * 768 * 2);
  ushort* apatch = mlp;
  ushort* wpatch = wq;

  // ---- patch embedding ----
  convt_kernel<<<dim3(24, 24), 256, 0, stream>>>(patch_w, wpatch, 768, 768);
  im2col_kernel<<<27648, 256, 0, stream>>>(img, apatch);
  gemmP_kernel<EPI_PATCH><<<72 * 6, 256, 0, stream>>>(
      apatch, wpatch, patch_b, pos_emb, x, 9216, 768, 768, 72);
  clspos_kernel<<<48, 256, 0, stream>>>(cls_tok, pos_emb, x);

  // ---- transformer layers ----
  for (int l = 0; l < 12; ++l) {
    wconv_kernel<<<6912, 256, 0, stream>>>(
        qkv_w + (size_t)l * 768 * 2304, out_w + (size_t)l * 768 * 768,
        ff1_w + (size_t)l * 768 * 3072, ff2_w + (size_t)l * 3072 * 768,
        wq, wo, w1, w2);
    ln_kernel<<<2308, 256, 0, stream>>>(x, ln1_w + l * 768, ln1_b + l * 768, h);
    gemm8_kernel<EPI_BF16><<<37 * 9, 512, 0, stream>>>(
        h, wq, nullptr, qkvb, 9232, 2304, 768, 9);
    attn_kernel<<<dim3(192, 10), 256, 0, stream>>>(qkvb, h);  // o -> h
    gemmP_kernel<EPI_RES_F32><<<73 * 6, 256, 0, stream>>>(
        h, wo, out_b + l * 768, x, x, 9232, 768, 768, 73);
    ln_kernel<<<2308, 256, 0, stream>>>(x, ln2_w + l * 768, ln2_b + l * 768, h);
    gemm8_kernel<EPI_GELU_BF16><<<37 * 12, 512, 0, stream>>>(
        h, w1, ff1_b + l * 3072, mlp, 9232, 3072, 768, 12);
    gemmP_kernel<EPI_RES_F32><<<73 * 6, 256, 0, stream>>>(
        mlp, w2, ff2_b + l * 768, x, x, 9232, 768, 3072, 73);
  }

  // ---- classification head ----
  head_kernel<<<dim3(16, 4), 256, 0, stream>>>(x, hln_w, hln_b, head_w, head_b, outp);
}

// Round 10
// 4054.347 us; speedup vs baseline: 1.1062x; 1.0288x over previous
//
#include <hip/hip_runtime.h>
#include <cstdint>

// ============================================================================
// ViT forward, MI355X round 10.
//   R10 changes vs R9:
//   - gemm8: 4 quadrant-phases -> 2 FAT phases per K-tile (32 MFMA each).
//     R9 showed ~1.0us/phase with only ~400cyc content -> per-phase overhead
//     dominates; halving phase count should cut block time ~40%.
//     FIFO: issue order A0,B0,B1,A1; waits vmcnt(2)/vmcnt(6); peel 2/0.
//   - head_kernel: grid (16,16), 4-way k-split + LDS reduce (was 64 blocks
//     scalar, 96us at 0.8% VALUBusy -> predict ~15us).
// ============================================================================

typedef __attribute__((ext_vector_type(8))) short bf16x8;
typedef __attribute__((ext_vector_type(4))) float f32x4;

#define NTOK 577

__device__ __forceinline__ ushort f2bf(float f) {
  union { float f; unsigned int u; } x; x.f = f;
  unsigned int r = x.u + 0x7fffu + ((x.u >> 16) & 1u);  // RNE
  return (ushort)(r >> 16);
}

__device__ __forceinline__ void gload_lds16(const ushort* g, ushort* l) {
  __builtin_amdgcn_global_load_lds(
      (const __attribute__((address_space(1))) unsigned int*)g,
      (__attribute__((address_space(3))) unsigned int*)l, 16, 0, 0);
}

#define VMCNT6 asm volatile("s_waitcnt vmcnt(6)" ::: "memory")
#define VMCNT2 asm volatile("s_waitcnt vmcnt(2)" ::: "memory")
#define VMCNT0 asm volatile("s_waitcnt vmcnt(0)" ::: "memory")
#define LGKM0  asm volatile("s_waitcnt lgkmcnt(0)" ::: "memory")
#define SCHED0 __builtin_amdgcn_sched_barrier(0)
#define BARRIER __builtin_amdgcn_s_barrier()

// rotation swizzle: logical 16B-granule at row -> physical granule rotation
__device__ __forceinline__ int gsw(int row) {
  return (row & 7) + 2 * ((row >> 4) & 3);
}

// ---------------------------------------------------------------------------
// 32x32 transpose tile body: W[K][N] f32 -> Wt[N][K] bf16
// ---------------------------------------------------------------------------
__device__ __forceinline__ void transpose_tile(const float* __restrict__ W,
                                               ushort* __restrict__ Wt,
                                               int K, int N, int kb, int nb,
                                               int tx, int ty, float t[32][33]) {
#pragma unroll
  for (int i = 0; i < 32; i += 8)
    t[ty + i][tx] = W[(size_t)(kb + ty + i) * N + (nb + tx)];
  __syncthreads();
#pragma unroll
  for (int i = 0; i < 32; i += 8)
    Wt[(size_t)(nb + ty + i) * K + (kb + tx)] = f2bf(t[tx][ty + i]);
}

// standalone (patch embedding weight)
__global__ __launch_bounds__(256) void convt_kernel(const float* __restrict__ W,
                                                    ushort* __restrict__ Wt,
                                                    int K, int N) {
  __shared__ float t[32][33];
  transpose_tile(W, Wt, K, N, blockIdx.x * 32, blockIdx.y * 32,
                 threadIdx.x & 31, threadIdx.x >> 5, t);
}

// fused per-layer: qkv_w, out_w, ff1_w, ff2_w in one launch (6912 blocks)
__global__ __launch_bounds__(256) void wconv_kernel(
    const float* __restrict__ qkv_w, const float* __restrict__ out_w,
    const float* __restrict__ ff1_w, const float* __restrict__ ff2_w,
    ushort* __restrict__ wq, ushort* __restrict__ wo,
    ushort* __restrict__ w1, ushort* __restrict__ w2) {
  __shared__ float t[32][33];
  const int tx = threadIdx.x & 31, ty = threadIdx.x >> 5;
  int bx = blockIdx.x;
  if (bx < 1728) {          // qkv: 768 x 2304 (24 x 72 tiles)
    transpose_tile(qkv_w, wq, 768, 2304, (bx % 24) * 32, (bx / 24) * 32, tx, ty, t);
  } else if (bx < 2304) {   // out: 768 x 768 (24 x 24)
    bx -= 1728;
    transpose_tile(out_w, wo, 768, 768, (bx % 24) * 32, (bx / 24) * 32, tx, ty, t);
  } else if (bx < 4608) {   // ff1: 768 x 3072 (24 x 96)
    bx -= 2304;
    transpose_tile(ff1_w, w1, 768, 3072, (bx % 24) * 32, (bx / 24) * 32, tx, ty, t);
  } else {                  // ff2: 3072 x 768 (96 x 24)
    bx -= 4608;
    transpose_tile(ff2_w, w2, 3072, 768, (bx % 96) * 32, (bx / 96) * 32, tx, ty, t);
  }
}

// ---------------------------------------------------------------------------
// im2col: img (B,3,384,384) f32 -> Apatch (9216 x 768) bf16
// ---------------------------------------------------------------------------
__global__ __launch_bounds__(256) void im2col_kernel(const float* __restrict__ img,
                                                     ushort* __restrict__ Ap) {
  const int idx = blockIdx.x * 256 + threadIdx.x;  // 9216*768 exactly
  const int j = idx % 768;
  const int m = idx / 768;
  const int c = j % 3;
  const int q = j / 3;
  const int px = q & 15, py = q >> 4;
  const int b = m / 576, p = m % 576;
  const int gy = p / 24, gx = p % 24;
  const float v = img[((size_t)(b * 3 + c) * 384 + (gy * 16 + py)) * 384 + (gx * 16 + px)];
  Ap[idx] = f2bf(v);
}

__global__ void clspos_kernel(const float* __restrict__ cls_tok,
                              const float* __restrict__ pos,
                              float* __restrict__ x) {
  const int i = blockIdx.x * 256 + threadIdx.x;  // 16*768
  const int b = i / 768, d = i % 768;
  x[(size_t)b * NTOK * 768 + d] = cls_tok[d] + pos[d];
}

// ---------------------------------------------------------------------------
// LayerNorm: 4 rows per 256-thread block (wave w -> row blockIdx*4 + w).
// ---------------------------------------------------------------------------
__global__ __launch_bounds__(256) void ln_kernel(const float* __restrict__ x,
                                                 const float* __restrict__ w,
                                                 const float* __restrict__ bb,
                                                 ushort* __restrict__ out) {
  const int wave = threadIdx.x >> 6, lane = threadIdx.x & 63;
  const int row = blockIdx.x * 4 + wave;
  const float4* xr = reinterpret_cast<const float4*>(x + (size_t)row * 768);
  const float4 v0 = xr[lane], v1 = xr[lane + 64], v2 = xr[lane + 128];
  float vals[12] = {v0.x, v0.y, v0.z, v0.w, v1.x, v1.y, v1.z, v1.w,
                    v2.x, v2.y, v2.z, v2.w};
  float s = 0.f;
#pragma unroll
  for (int i = 0; i < 12; ++i) s += vals[i];
#pragma unroll
  for (int o = 32; o; o >>= 1) s += __shfl_xor(s, o);
  const float mu = s * (1.0f / 768.0f);
  float q = 0.f;
#pragma unroll
  for (int i = 0; i < 12; ++i) { const float d = vals[i] - mu; q += d * d; }
#pragma unroll
  for (int o = 32; o; o >>= 1) q += __shfl_xor(q, o);
  const float rstd = rsqrtf(q * (1.0f / 768.0f) + 1e-5f);
  const float4* w4 = reinterpret_cast<const float4*>(w);
  const float4* b4 = reinterpret_cast<const float4*>(bb);
  ushort* orow = out + (size_t)row * 768;
#pragma unroll
  for (int ch = 0; ch < 3; ++ch) {
    const float4 wv = w4[lane + ch * 64];
    const float4 bv = b4[lane + ch * 64];
    ushort4 u;
    u.x = f2bf((vals[ch * 4 + 0] - mu) * rstd * wv.x + bv.x);
    u.y = f2bf((vals[ch * 4 + 1] - mu) * rstd * wv.y + bv.y);
    u.z = f2bf((vals[ch * 4 + 2] - mu) * rstd * wv.z + bv.z);
    u.w = f2bf((vals[ch * 4 + 3] - mu) * rstd * wv.w + bv.w);
    *reinterpret_cast<ushort4*>(orow + ch * 256 + lane * 4) = u;
  }
}

// ---------------------------------------------------------------------------
// Epilogue IDs
// ---------------------------------------------------------------------------
constexpr int EPI_BF16 = 0;       // C = acc                     -> bf16
constexpr int EPI_GELU_BF16 = 1;  // C = gelu(acc + bias)        -> bf16
constexpr int EPI_RES_F32 = 2;    // C = acc + bias + extra[r,c] -> f32
constexpr int EPI_PATCH = 3;      // x[row+b+1] = acc + patch_b + pos[p+1]

// ---------------------------------------------------------------------------
// 256x256 MFMA GEMM (qkv / ff1), 2 FAT phases per K-tile (32 MFMA each).
// N-fast mapping. Issue order per tile: A0, B0, B1, A1.
// Main loop waits: phase0 vmcnt(2) [A0,B0,B1 of t landed], phase1 vmcnt(6)
// [A1 of t landed]. Peeled last tile: vmcnt(2) / vmcnt(0).
// ---------------------------------------------------------------------------
template <int EPI>
__global__ __launch_bounds__(512, 2) void gemm8_kernel(
    const ushort* __restrict__ A, const ushort* __restrict__ Bt,
    const float* __restrict__ bias, void* __restrict__ Cptr,
    int M, int N, int K, int nt) {
  __shared__ ushort lds[2][2][16384];  // [buf][A/B][row*64 + phys]

  const int nwg = gridDim.x;
  const int orig = blockIdx.x;
  const int q8 = nwg >> 3, r8 = nwg & 7, xcd = orig & 7, sidx = orig >> 3;
  const int wg = (xcd < r8 ? xcd * (q8 + 1) : r8 * (q8 + 1) + (xcd - r8) * q8) + sidx;
  const int tileM = (wg / nt) * 256;   // slow: A-band per XCD chunk
  const int tileN = (wg % nt) * 256;   // fast: sweep N within the band

  const int tid = threadIdx.x;
  const int wave = tid >> 6, lane = tid & 63;
  const int wm = wave >> 2, wn = wave & 3;
  const int lr = lane & 15, lg = lane >> 4;

  f32x4 acc[8][4];
#pragma unroll
  for (int i = 0; i < 8; ++i)
#pragma unroll
    for (int j = 0; j < 4; ++j) acc[i][j] = (f32x4){0.f, 0.f, 0.f, 0.f};

  int rsA[2][2], rsB[2][2];
  const ushort* pA[2][2];
  const ushort* pB[2][2];
#pragma unroll
  for (int h = 0; h < 2; ++h)
#pragma unroll
    for (int g = 0; g < 2; ++g) {
      const int c = wave * 2 + g;
      {
        const int rowst = h * 64 + ((c >> 3) << 7) + ((c & 7) << 3);
        rsA[h][g] = rowst;
        const int row = rowst + (lane >> 3);
        const int lgr = ((lane & 7) - gsw(row)) & 7;
        pA[h][g] = A + (size_t)(tileM + row) * K + lgr * 8;
      }
      {
        const int rowst = h * 32 + ((c >> 2) << 6) + ((c & 3) << 3);
        rsB[h][g] = rowst;
        const int row = rowst + (lane >> 3);
        const int lgr = ((lane & 7) - gsw(row)) & 7;
        pB[h][g] = Bt + (size_t)(tileN + row) * K + lgr * 8;
      }
    }

#define STAGE_A(h, buf, k1)                                   \
  gload_lds16(pA[h][0] + (k1), &lds[buf][0][rsA[h][0] * 64]); \
  gload_lds16(pA[h][1] + (k1), &lds[buf][0][rsA[h][1] * 64]);
#define STAGE_B(h, buf, k1)                                   \
  gload_lds16(pB[h][0] + (k1), &lds[buf][1][rsB[h][0] * 64]); \
  gload_lds16(pB[h][1] + (k1), &lds[buf][1][rsB[h][1] * 64]);

  bf16x8 areg[8], breg[8];
#define LDA8(h, buf)                                                          \
  {                                                                           \
    const ushort* base = &lds[buf][0][0];                                     \
    _Pragma("unroll") for (int mf = 0; mf < 4; ++mf) {                        \
      const int row = wm * 128 + (h) * 64 + mf * 16 + lr;                     \
      _Pragma("unroll") for (int ks = 0; ks < 2; ++ks) {                      \
        const int pg = (ks * 4 + lg + (lr & 7) + 2 * mf) & 7;                 \
        areg[mf * 2 + ks] =                                                   \
            *reinterpret_cast<const bf16x8*>(&base[row * 64 + pg * 8]);       \
      }                                                                       \
    }                                                                         \
  }
#define LDB8(buf)                                                             \
  {                                                                           \
    const ushort* base = &lds[buf][1][0];                                     \
    _Pragma("unroll") for (int q = 0; q < 2; ++q)                             \
        _Pragma("unroll") for (int nf = 0; nf < 2; ++nf) {                    \
      const int row = wn * 64 + q * 32 + nf * 16 + lr;                        \
      _Pragma("unroll") for (int ks = 0; ks < 2; ++ks) {                      \
        const int pg = (ks * 4 + lg + (lr & 7) + 2 * ((q * 2 + nf) & 3)) & 7; \
        breg[q * 4 + nf * 2 + ks] =                                           \
            *reinterpret_cast<const bf16x8*>(&base[row * 64 + pg * 8]);       \
      }                                                                       \
    }                                                                         \
  }
#define MFMA32(h)                                                           \
  __builtin_amdgcn_s_setprio(1);                                            \
  _Pragma("unroll") for (int q = 0; q < 2; ++q)                             \
      _Pragma("unroll") for (int mf = 0; mf < 4; ++mf)                      \
          _Pragma("unroll") for (int nf = 0; nf < 2; ++nf)                  \
              _Pragma("unroll") for (int ks = 0; ks < 2; ++ks)              \
                  acc[(h)*4 + mf][q * 2 + nf] =                             \
                      __builtin_amdgcn_mfma_f32_16x16x32_bf16(              \
                          areg[mf * 2 + ks], breg[q * 4 + nf * 2 + ks],     \
                          acc[(h)*4 + mf][q * 2 + nf], 0, 0, 0);            \
  __builtin_amdgcn_s_setprio(0);

  // prologue: K-tile 0 into buf 0, FIFO order A0, B0, B1, A1
  STAGE_A(0, 0, 0);
  STAGE_B(0, 0, 0);
  STAGE_B(1, 0, 0);
  STAGE_A(1, 0, 0);

  const int NT = K >> 6;
  for (int t = 0; t < NT - 1; ++t) {
    const int cb = t & 1, nb = (t + 1) & 1;
    const int k1 = (t + 1) * 64;
    // phase 0: A-half 0 x all B; stage A0,B0,B1 of t+1
    VMCNT2; SCHED0;
    BARRIER;
    LDA8(0, cb);
    LDB8(cb);
    STAGE_A(0, nb, k1);
    STAGE_B(0, nb, k1);
    STAGE_B(1, nb, k1);
    LGKM0; SCHED0;
    MFMA32(0);
    // phase 1: A-half 1 x all B; stage A1 of t+1
    VMCNT6; SCHED0;
    BARRIER;
    LDA8(1, cb);
    STAGE_A(1, nb, k1);
    LGKM0; SCHED0;
    MFMA32(1);
  }

  {  // peeled last K-tile: no stages; drain 8 -> 2 -> 0
    const int cb = (NT - 1) & 1;
    VMCNT2; SCHED0;
    BARRIER;
    LDA8(0, cb);
    LDB8(cb);
    LGKM0; SCHED0;
    MFMA32(0);
    VMCNT0; SCHED0;
    BARRIER;
    LDA8(1, cb);
    LGKM0; SCHED0;
    MFMA32(1);
  }

#pragma unroll
  for (int am = 0; am < 8; ++am) {
#pragma unroll
    for (int r = 0; r < 4; ++r) {
      const int row = tileM + wm * 128 + (am >> 2) * 64 + (am & 3) * 16 + lg * 4 + r;
      if (row >= M) continue;
#pragma unroll
      for (int an = 0; an < 4; ++an) {
        const int col = tileN + wn * 64 + (an >> 1) * 32 + (an & 1) * 16 + lr;
        float v = acc[am][an][r];
        if constexpr (EPI == EPI_BF16) {
          reinterpret_cast<ushort*>(Cptr)[(size_t)row * N + col] = f2bf(v);
        } else {  // EPI_GELU_BF16
          v += bias[col];
          v = 0.5f * v * (1.0f + erff(v * 0.70710678118654752440f));
          reinterpret_cast<ushort*>(Cptr)[(size_t)row * N + col] = f2bf(v);
        }
      }
    }
  }
#undef STAGE_A
#undef STAGE_B
#undef LDA8
#undef LDB8
#undef MFMA32
}

// ---------------------------------------------------------------------------
// gemmP: 128x128, BK=64, dbuf 64 KiB (2 blocks/CU). For patch / proj / ff2.
// ---------------------------------------------------------------------------
template <int EPI>
__global__ __launch_bounds__(256) void gemmP_kernel(
    const ushort* __restrict__ A, const ushort* __restrict__ Bt,
    const float* __restrict__ bias, const float* __restrict__ extra,
    void* __restrict__ Cptr, int M, int N, int K, int mt) {
  __shared__ ushort ldsA[2][128 * 64];
  __shared__ ushort ldsB[2][128 * 64];

  const int nwg = gridDim.x;
  const int orig = blockIdx.x;
  const int q8 = nwg >> 3, r8 = nwg & 7, xcd = orig & 7, sidx = orig >> 3;
  const int wg = (xcd < r8 ? xcd * (q8 + 1) : r8 * (q8 + 1) + (xcd - r8) * q8) + sidx;
  const int tileM = (wg % mt) * 128;
  const int tileN = (wg / mt) * 128;

  const int tid = threadIdx.x;
  const int wave = tid >> 6, lane = tid & 63;
  const int wm = wave >> 1, wn = wave & 1;
  const int lr = lane & 15, lg = lane >> 4;

  f32x4 acc[4][4];
#pragma unroll
  for (int m = 0; m < 4; ++m)
#pragma unroll
    for (int n = 0; n < 4; ++n) acc[m][n] = (f32x4){0.f, 0.f, 0.f, 0.f};

  const ushort* pA[4];
  const ushort* pB[4];
  int dst[4];
#pragma unroll
  for (int i = 0; i < 4; ++i) {
    const int c = wave * 4 + i;
    const int rowst = c * 8;
    dst[i] = rowst * 64;
    const int row = rowst + (lane >> 3);
    const int lgr = ((lane & 7) - gsw(row)) & 7;
    pA[i] = A + (size_t)(tileM + row) * K + lgr * 8;
    pB[i] = Bt + (size_t)(tileN + row) * K + lgr * 8;
  }

#define PSTAGE(buf, kk)                              \
  _Pragma("unroll") for (int i = 0; i < 4; ++i)      \
      gload_lds16(pA[i] + (kk), &ldsA[buf][dst[i]]); \
  _Pragma("unroll") for (int i = 0; i < 4; ++i)      \
      gload_lds16(pB[i] + (kk), &ldsB[buf][dst[i]]);

  PSTAGE(0, 0);

  const int NT = K >> 6;
  int cb = 0;
  for (int t = 0; t < NT; ++t) {
    VMCNT0; SCHED0;
    BARRIER;
    if (t + 1 < NT) { PSTAGE(cb ^ 1, (t + 1) * 64); }
    bf16x8 a[8], b[8];
#pragma unroll
    for (int mf = 0; mf < 4; ++mf) {
      const int row = wm * 64 + mf * 16 + lr;
#pragma unroll
      for (int ks = 0; ks < 2; ++ks) {
        const int pg = (ks * 4 + lg + (lr & 7) + 2 * mf) & 7;
        a[mf * 2 + ks] = *reinterpret_cast<const bf16x8*>(&ldsA[cb][row * 64 + pg * 8]);
      }
    }
#pragma unroll
    for (int nf = 0; nf < 4; ++nf) {
      const int row = wn * 64 + nf * 16 + lr;
#pragma unroll
      for (int ks = 0; ks < 2; ++ks) {
        const int pg = (ks * 4 + lg + (lr & 7) + 2 * nf) & 7;
        b[nf * 2 + ks] = *reinterpret_cast<const bf16x8*>(&ldsB[cb][row * 64 + pg * 8]);
      }
    }
    LGKM0; SCHED0;
    __builtin_amdgcn_s_setprio(1);
#pragma unroll
    for (int mf = 0; mf < 4; ++mf)
#pragma unroll
      for (int nf = 0; nf < 4; ++nf)
#pragma unroll
        for (int ks = 0; ks < 2; ++ks)
          acc[mf][nf] = __builtin_amdgcn_mfma_f32_16x16x32_bf16(
              a[mf * 2 + ks], b[nf * 2 + ks], acc[mf][nf], 0, 0, 0);
    __builtin_amdgcn_s_setprio(0);
    cb ^= 1;
  }

#pragma unroll
  for (int mf = 0; mf < 4; ++mf) {
#pragma unroll
    for (int r = 0; r < 4; ++r) {
      const int row = tileM + wm * 64 + mf * 16 + lg * 4 + r;
      if (row >= M) continue;
#pragma unroll
      for (int nf = 0; nf < 4; ++nf) {
        const int col = tileN + wn * 64 + nf * 16 + lr;
        float v = acc[mf][nf][r];
        if constexpr (EPI == EPI_BF16) {
          reinterpret_cast<ushort*>(Cptr)[(size_t)row * N + col] = f2bf(v);
        } else if constexpr (EPI == EPI_GELU_BF16) {
          v += bias[col];
          v = 0.5f * v * (1.0f + erff(v * 0.70710678118654752440f));
          reinterpret_cast<ushort*>(Cptr)[(size_t)row * N + col] = f2bf(v);
        } else if constexpr (EPI == EPI_RES_F32) {
          v += bias[col] + extra[(size_t)row * N + col];
          reinterpret_cast<float*>(Cptr)[(size_t)row * N + col] = v;
        } else {  // EPI_PATCH
          const int bb = row / 576;
          const int p = row - bb * 576;
          v += bias[col] + extra[(size_t)(p + 1) * 768 + col];
          reinterpret_cast<float*>(Cptr)[(size_t)(row + bb + 1) * 768 + col] = v;
        }
      }
    }
  }
#undef PSTAGE
}

// ---------------------------------------------------------------------------
// MFMA flash attention with rotation-swizzled LDS. Unchanged.
// ---------------------------------------------------------------------------
__global__ __launch_bounds__(256) void attn_kernel(const ushort* __restrict__ qkv,
                                                   ushort* __restrict__ o) {
  __shared__ ushort sK[64 * 64];
  __shared__ ushort sVt[64 * 64];
  __shared__ ushort sP[4][16 * 72];
  const int bh = blockIdx.x;
  const int b = bh / 12, hh = bh % 12;
  const int q0 = blockIdx.y * 64;
  const int tid = threadIdx.x;
  const int wave = tid >> 6, lane = tid & 63;
  const int lr = lane & 15;
  const int lg = lane >> 4;
  const ushort* base = qkv + (size_t)b * NTOK * 2304 + hh * 64;
  const float SC = 0.03608439182435161f;  // 768^-0.5

  bf16x8 qf[2];
  {
    const int qrow = q0 + wave * 16 + lr;
    if (qrow < NTOK) {
      const ushort* qp = base + (size_t)qrow * 2304 + lg * 8;
      qf[0] = *reinterpret_cast<const bf16x8*>(qp);
      qf[1] = *reinterpret_cast<const bf16x8*>(qp + 32);
    } else {
      qf[0] = (bf16x8){0, 0, 0, 0, 0, 0, 0, 0};
      qf[1] = qf[0];
    }
  }

  float mst[4], lst[4];
  f32x4 oacc[4];
#pragma unroll
  for (int i = 0; i < 4; ++i) {
    mst[i] = -1e30f; lst[i] = 0.f;
    oacc[i] = (f32x4){0.f, 0.f, 0.f, 0.f};
  }

  const int skey = tid >> 2;
  const int sc4 = tid & 3;
  const int gswk = gsw(skey);

  for (int t0 = 0; t0 < NTOK; t0 += 64) {
    __syncthreads();
    {
      const int gk = t0 + skey;
      int4 k0v, k1v, v0v, v1v;
      if (gk < NTOK) {
        const int4* kp = reinterpret_cast<const int4*>(base + (size_t)gk * 2304 + 768 + sc4 * 16);
        k0v = kp[0]; k1v = kp[1];
        const int4* vp = reinterpret_cast<const int4*>(base + (size_t)gk * 2304 + 1536 + sc4 * 16);
        v0v = vp[0]; v1v = vp[1];
      } else {
        int4 z; z.x = z.y = z.z = z.w = 0;
        k0v = k1v = v0v = v1v = z;
      }
      *reinterpret_cast<int4*>(&sK[skey * 64 + (((2 * sc4 + 0) + gswk) & 7) * 8]) = k0v;
      *reinterpret_cast<int4*>(&sK[skey * 64 + (((2 * sc4 + 1) + gswk) & 7) * 8]) = k1v;
      const ushort* vs = reinterpret_cast<const ushort*>(&v0v);
      const ushort* vs2 = reinterpret_cast<const ushort*>(&v1v);
#pragma unroll
      for (int i = 0; i < 8; ++i) {
        const int d0 = sc4 * 16 + i;
        const int pg0 = ((skey >> 3) + gsw(d0)) & 7;
        sVt[d0 * 64 + pg0 * 8 + (skey & 7)] = vs[i];
        const int d1 = sc4 * 16 + 8 + i;
        const int pg1 = ((skey >> 3) + gsw(d1)) & 7;
        sVt[d1 * 64 + pg1 * 8 + (skey & 7)] = vs2[i];
      }
    }
    __syncthreads();

    f32x4 sacc[4];
#pragma unroll
    for (int n = 0; n < 4; ++n) sacc[n] = (f32x4){0.f, 0.f, 0.f, 0.f};
#pragma unroll
    for (int n = 0; n < 4; ++n) {
      const int row = n * 16 + lr;
      const int rot = (lr & 7) + 2 * n;
      const bf16x8 kf0 = *reinterpret_cast<const bf16x8*>(&sK[row * 64 + ((lg + rot) & 7) * 8]);
      const bf16x8 kf1 = *reinterpret_cast<const bf16x8*>(&sK[row * 64 + ((4 + lg + rot) & 7) * 8]);
      sacc[n] = __builtin_amdgcn_mfma_f32_16x16x32_bf16(qf[0], kf0, sacc[n], 0, 0, 0);
      sacc[n] = __builtin_amdgcn_mfma_f32_16x16x32_bf16(qf[1], kf1, sacc[n], 0, 0, 0);
    }

    float s[4][4], pm[4];
#pragma unroll
    for (int reg = 0; reg < 4; ++reg) pm[reg] = -1e30f;
#pragma unroll
    for (int n = 0; n < 4; ++n)
#pragma unroll
      for (int reg = 0; reg < 4; ++reg) {
        float v = sacc[n][reg] * SC;
        if (t0 + n * 16 + lr >= NTOK) v = -1e30f;
        s[n][reg] = v;
        pm[reg] = fmaxf(pm[reg], v);
      }
#pragma unroll
    for (int off = 1; off < 16; off <<= 1)
#pragma unroll
      for (int reg = 0; reg < 4; ++reg) pm[reg] = fmaxf(pm[reg], __shfl_xor(pm[reg], off));

    float al[4], rs[4];
#pragma unroll
    for (int reg = 0; reg < 4; ++reg) {
      const float mn = fmaxf(mst[reg], pm[reg]);
      al[reg] = __expf(mst[reg] - mn);
      mst[reg] = mn;
      rs[reg] = 0.f;
    }
#pragma unroll
    for (int n = 0; n < 4; ++n)
#pragma unroll
      for (int reg = 0; reg < 4; ++reg) {
        s[n][reg] = __expf(s[n][reg] - mst[reg]);
        rs[reg] += s[n][reg];
      }
#pragma unroll
    for (int off = 1; off < 16; off <<= 1)
#pragma unroll
      for (int reg = 0; reg < 4; ++reg) rs[reg] += __shfl_xor(rs[reg], off);
#pragma unroll
    for (int reg = 0; reg < 4; ++reg) {
      lst[reg] = lst[reg] * al[reg] + rs[reg];
#pragma unroll
      for (int n = 0; n < 4; ++n) oacc[n][reg] *= al[reg];
    }

#pragma unroll
    for (int n = 0; n < 4; ++n)
#pragma unroll
      for (int reg = 0; reg < 4; ++reg)
        sP[wave][(lg * 4 + reg) * 72 + n * 16 + lr] = f2bf(s[n][reg]);

    const bf16x8 pf0 = *reinterpret_cast<const bf16x8*>(&sP[wave][lr * 72 + lg * 8]);
    const bf16x8 pf1 = *reinterpret_cast<const bf16x8*>(&sP[wave][lr * 72 + 32 + lg * 8]);
#pragma unroll
    for (int n = 0; n < 4; ++n) {
      const int row = n * 16 + lr;
      const int rot = (lr & 7) + 2 * n;
      const bf16x8 vf0 = *reinterpret_cast<const bf16x8*>(&sVt[row * 64 + ((lg + rot) & 7) * 8]);
      const bf16x8 vf1 = *reinterpret_cast<const bf16x8*>(&sVt[row * 64 + ((4 + lg + rot) & 7) * 8]);
      oacc[n] = __builtin_amdgcn_mfma_f32_16x16x32_bf16(pf0, vf0, oacc[n], 0, 0, 0);
      oacc[n] = __builtin_amdgcn_mfma_f32_16x16x32_bf16(pf1, vf1, oacc[n], 0, 0, 0);
    }
  }

#pragma unroll
  for (int reg = 0; reg < 4; ++reg) {
    const int q = q0 + wave * 16 + lg * 4 + reg;
    if (q >= NTOK) continue;
    const float inv = 1.0f / lst[reg];
    ushort* op = o + (size_t)(b * NTOK + q) * 768 + hh * 64;
#pragma unroll
    for (int n = 0; n < 4; ++n) op[n * 16 + lr] = f2bf(oacc[n][reg] * inv);
  }
}

// ---------------------------------------------------------------------------
// Head: grid (16 b, 16 col-tiles of 64), 256 thr. LN(cls row) then 4-way
// k-split dot products + LDS reduce. hw reads coalesced (64 consecutive c).
// ---------------------------------------------------------------------------
__global__ __launch_bounds__(256) void head_kernel(const float* __restrict__ x,
                                                   const float* __restrict__ lw,
                                                   const float* __restrict__ lb,
                                                   const float* __restrict__ hw,
                                                   const float* __restrict__ hb,
                                                   float* __restrict__ out) {
  __shared__ float srow[768];
  __shared__ float sred[8];
  __shared__ float spart[4][64];
  const int b = blockIdx.x, ct = blockIdx.y, tid = threadIdx.x;
  const float* xr = x + (size_t)b * NTOK * 768;
  for (int i = tid; i < 768; i += 256) srow[i] = xr[i];
  __syncthreads();
  float part = srow[tid] + srow[tid + 256] + srow[tid + 512];
#pragma unroll
  for (int off = 32; off; off >>= 1) part += __shfl_xor(part, off);
  if ((tid & 63) == 0) sred[tid >> 6] = part;
  __syncthreads();
  const float mu = (sred[0] + sred[1] + sred[2] + sred[3]) * (1.0f / 768.0f);
  const float d0 = srow[tid] - mu, d1 = srow[tid + 256] - mu, d2 = srow[tid + 512] - mu;
  float vp = d0 * d0 + d1 * d1 + d2 * d2;
#pragma unroll
  for (int off = 32; off; off >>= 1) vp += __shfl_xor(vp, off);
  if ((tid & 63) == 0) sred[4 + (tid >> 6)] = vp;
  __syncthreads();
  const float rstd = rsqrtf((sred[4] + sred[5] + sred[6] + sred[7]) * (1.0f / 768.0f) + 1e-5f);
  for (int i = tid; i < 768; i += 256) srow[i] = (srow[i] - mu) * rstd * lw[i] + lb[i];
  __syncthreads();
  const int cl = tid & 63, kq = tid >> 6;
  const int c = ct * 64 + cl;
  float a = 0.f;
  if (c < 1000) {
    const int k0 = kq * 192;
#pragma unroll 8
    for (int k = k0; k < k0 + 192; ++k) a += srow[k] * hw[(size_t)k * 1000 + c];
  }
  spart[kq][cl] = a;
  __syncthreads();
  if (tid < 64) {
    const int c2 = ct * 64 + tid;
    if (c2 < 1000)
      out[b * 1000 + c2] =
          spart[0][tid] + spart[1][tid] + spart[2][tid] + spart[3][tid] + hb[c2];
  }
}

// ---------------------------------------------------------------------------
extern "C" void kernel_launch(void* const* d_in, const int* in_sizes, int n_in,
                              void* d_out, int out_size, void* d_ws, size_t ws_size,
                              hipStream_t stream) {
  const float* img     = (const float*)d_in[0];
  const float* patch_w = (const float*)d_in[1];
  const float* patch_b = (const float*)d_in[2];
  const float* pos_emb = (const float*)d_in[3];
  const float* cls_tok = (const float*)d_in[4];
  const float* ln1_w   = (const float*)d_in[5];
  const float* ln1_b   = (const float*)d_in[6];
  const float* qkv_w   = (const float*)d_in[7];
  const float* out_w   = (const float*)d_in[8];
  const float* out_b   = (const float*)d_in[9];
  const float* ln2_w   = (const float*)d_in[10];
  const float* ln2_b   = (const float*)d_in[11];
  const float* ff1_w   = (const float*)d_in[12];
  const float* ff1_b   = (const float*)d_in[13];
  const float* ff2_w   = (const float*)d_in[14];
  const float* ff2_b   = (const float*)d_in[15];
  const float* hln_w   = (const float*)d_in[16];
  const float* hln_b   = (const float*)d_in[17];
  const float* head_w  = (const float*)d_in[18];
  const float* head_b  = (const float*)d_in[19];
  float* outp = (float*)d_out;

  char* wsp = (char*)d_ws;
  auto alloc = [&](size_t bytes) {
    char* p = wsp;
    wsp += (bytes + 255) & ~(size_t)255;
    return p;
  };
  float*  x    = (float*) alloc((size_t)9232 * 768 * 4);
  ushort* h    = (ushort*)alloc((size_t)9232 * 768 * 2);
  ushort* qkvb = (ushort*)alloc((size_t)9232 * 2304 * 2);
  ushort* mlp  = (ushort*)alloc((size_t)9232 * 3072 * 2);
  ushort* wq   = (ushort*)alloc((size_t)768 * 2304 * 2);
  ushort* wo   = (ushort*)alloc((size_t)768 * 768 * 2);
  ushort* w1   = (ushort*)alloc((size_t)768 * 3072 * 2);
  ushort* w2   = (ushort*)alloc((size_t)3072 * 768 * 2);
  ushort* apatch = mlp;
  ushort* wpatch = wq;

  // ---- patch embedding ----
  convt_kernel<<<dim3(24, 24), 256, 0, stream>>>(patch_w, wpatch, 768, 768);
  im2col_kernel<<<27648, 256, 0, stream>>>(img, apatch);
  gemmP_kernel<EPI_PATCH><<<72 * 6, 256, 0, stream>>>(
      apatch, wpatch, patch_b, pos_emb, x, 9216, 768, 768, 72);
  clspos_kernel<<<48, 256, 0, stream>>>(cls_tok, pos_emb, x);

  // ---- transformer layers ----
  for (int l = 0; l < 12; ++l) {
    wconv_kernel<<<6912, 256, 0, stream>>>(
        qkv_w + (size_t)l * 768 * 2304, out_w + (size_t)l * 768 * 768,
        ff1_w + (size_t)l * 768 * 3072, ff2_w + (size_t)l * 3072 * 768,
        wq, wo, w1, w2);
    ln_kernel<<<2308, 256, 0, stream>>>(x, ln1_w + l * 768, ln1_b + l * 768, h);
    gemm8_kernel<EPI_BF16><<<37 * 9, 512, 0, stream>>>(
        h, wq, nullptr, qkvb, 9232, 2304, 768, 9);
    attn_kernel<<<dim3(192, 10), 256, 0, stream>>>(qkvb, h);  // o -> h
    gemmP_kernel<EPI_RES_F32><<<73 * 6, 256, 0, stream>>>(
        h, wo, out_b + l * 768, x, x, 9232, 768, 768, 73);
    ln_kernel<<<2308, 256, 0, stream>>>(x, ln2_w + l * 768, ln2_b + l * 768, h);
    gemm8_kernel<EPI_GELU_BF16><<<37 * 12, 512, 0, stream>>>(
        h, w1, ff1_b + l * 3072, mlp, 9232, 3072, 768, 12);
    gemmP_kernel<EPI_RES_F32><<<73 * 6, 256, 0, stream>>>(
        mlp, w2, ff2_b + l * 768, x, x, 9232, 768, 3072, 73);
  }

  // ---- classification head ----
  head_kernel<<<dim3(16, 16), 256, 0, stream>>>(x, hln_w, hln_b, head_w, head_b, outp);
}